// Round 8
// baseline (4862.679 us; speedup 1.0000x reference)
//
#include <hip/hip_runtime.h>
#include <stdint.h>

#define NPTS 400000
#define NVOX 281600
#define TPB  256
#define NBLK ((NPTS + TPB - 1) / TPB)
#define OUTN (NVOX * 128)

// XLA-style binning: division by constant folded to multiply-by-reciprocal
// in f32 (1/0.2f == 5.0f exactly, 1/4.0f == 0.25f exactly). DO NOT CHANGE:
// this exact form is what matches the golden (round 6->7 was the proof).
__device__ __forceinline__ int bin3(const float* __restrict__ pt,
                                    int& bx, int& by, int& bz) {
  float x = pt[1], y = pt[2], z = pt[3];
  bx = (int)fminf(fmaxf(floorf(x * 5.0f), 0.f), 351.f);
  by = (int)fminf(fmaxf(floorf((y + 40.f) * 5.0f), 0.f), 399.f);
  bz = (int)fminf(fmaxf(floorf((z + 3.f) * 0.25f), 0.f), 0.f);
  return (((int)pt[0] + bz) * 400 + by) * 352 + bx;
}

__device__ __forceinline__ int mkfeat(const float* __restrict__ pt,
    const float* __restrict__ vcnt, const float* __restrict__ vsx,
    const float* __restrict__ vsy, const float* __restrict__ vsz,
    float* f) {
  int bx, by, bz;
  int v = bin3(pt, bx, by, bz);
  float x = pt[1], y = pt[2], z = pt[3];
  float n = fmaxf(vcnt[v], 1.f);
  f[0] = x;  f[1] = y;  f[2] = z;  f[3] = pt[4];
  f[4] = x - vsx[v] / n;
  f[5] = y - vsy[v] / n;
  f[6] = z - vsz[v] / n;
  f[7] = x - (0.2f * (float)bx + 0.1f);
  f[8] = y - (0.2f * (float)by - 39.9f);
  f[9] = z - (4.0f * (float)bz - 1.0f);
  return v;
}

__device__ __forceinline__ float h0c(const float* f,
                                     const float* __restrict__ W0, int c) {
  float h = f[0] * W0[c];
  #pragma unroll
  for (int i = 1; i < 10; ++i) h = fmaf(f[i], W0[i * 64 + c], h);
  return h;
}

__global__ __launch_bounds__(256) void voxsum(const float* __restrict__ pts,
    float* __restrict__ vcnt, float* __restrict__ vsx,
    float* __restrict__ vsy, float* __restrict__ vsz) {
  int p = blockIdx.x * TPB + threadIdx.x;
  if (p >= NPTS) return;
  const float* pt = pts + (size_t)p * 5;
  int bx, by, bz;
  int v = bin3(pt, bx, by, bz);
  atomicAdd(&vcnt[v], 1.f);
  atomicAdd(&vsx[v], pt[1]);
  atomicAdd(&vsy[v], pt[2]);
  atomicAdd(&vsz[v], pt[3]);
}

__global__ __launch_bounds__(256) void bn0stats(const float* __restrict__ pts,
    const float* __restrict__ vcnt, const float* __restrict__ vsx,
    const float* __restrict__ vsy, const float* __restrict__ vsz,
    const float* __restrict__ W0,
    double* __restrict__ gs, double* __restrict__ gq) {
  __shared__ float bs[4][64], bq[4][64];
  int t = threadIdx.x, wv = t >> 6, ln = t & 63;
  int p = blockIdx.x * TPB + t;
  bool ok = p < NPTS;
  const float* pt = pts + (size_t)(ok ? p : 0) * 5;
  float f[10];
  mkfeat(pt, vcnt, vsx, vsy, vsz, f);
  for (int c = 0; c < 64; ++c) {
    float h = ok ? h0c(f, W0, c) : 0.f;
    float q = h * h;
    #pragma unroll
    for (int m = 1; m < 64; m <<= 1) {
      h += __shfl_xor(h, m, 64);
      q += __shfl_xor(q, m, 64);
    }
    if (ln == 0) { bs[wv][c] = h; bq[wv][c] = q; }
  }
  __syncthreads();
  if (t < 64) {
    atomicAdd(&gs[t], (double)bs[0][t] + bs[1][t] + bs[2][t] + bs[3][t]);
    atomicAdd(&gq[t], (double)bq[0][t] + bq[1][t] + bq[2][t] + bq[3][t]);
  }
}

__global__ void bnfold(const double* __restrict__ gs, const double* __restrict__ gq,
                       const float* __restrict__ gam, const float* __restrict__ bet,
                       float* __restrict__ sc, float* __restrict__ sh, int C) {
  int c = threadIdx.x;
  if (c >= C) return;
  double mu  = gs[c] / (double)NPTS;
  double var = gq[c] / (double)NPTS - mu * mu;
  double s = (double)gam[c] / sqrt(var + 1e-3);
  sc[c] = (float)s;
  sh[c] = (float)((double)bet[c] - mu * s);
}

__global__ __launch_bounds__(256) void pf0max(const float* __restrict__ pts,
    const float* __restrict__ vcnt, const float* __restrict__ vsx,
    const float* __restrict__ vsy, const float* __restrict__ vsz,
    const float* __restrict__ W0, const float* __restrict__ sc0,
    const float* __restrict__ sh0, unsigned int* __restrict__ vmax) {
  int p = blockIdx.x * TPB + threadIdx.x;
  if (p >= NPTS) return;
  const float* pt = pts + (size_t)p * 5;
  float f[10];
  int v = mkfeat(pt, vcnt, vsx, vsy, vsz, f);
  unsigned int* row = vmax + (size_t)v * 64;
  for (int c = 0; c < 64; ++c) {
    float pf = fmaxf(fmaf(h0c(f, W0, c), sc0[c], sh0[c]), 0.f);
    atomicMax(&row[c], __float_as_uint(pf));
  }
}

template <int STATS, int CB>
__global__ __launch_bounds__(256, 1) void layer1(const float* __restrict__ pts,
    const float* __restrict__ vcnt, const float* __restrict__ vsx,
    const float* __restrict__ vsy, const float* __restrict__ vsz,
    const float* __restrict__ W0, const float* __restrict__ sc0,
    const float* __restrict__ sh0, const unsigned int* __restrict__ vmax,
    const float* __restrict__ W1,
    double* __restrict__ gs, double* __restrict__ gq,
    const float* __restrict__ sc1, const float* __restrict__ sh1,
    unsigned int* __restrict__ outp) {
  __shared__ float bs[4][64], bq[4][64];
  int t = threadIdx.x, wv = t >> 6, ln = t & 63;
  int p = blockIdx.x * TPB + t;
  bool ok = p < NPTS;
  const float* pt = pts + (size_t)(ok ? p : 0) * 5;
  float f[10];
  int v = mkfeat(pt, vcnt, vsx, vsy, vsz, f);

  // acc[] must be register-resident: EVERY access below uses a
  // compile-time-constant index (all loops touching acc are unrolled).
  // Rule #20: one runtime-indexed access sends the array to scratch
  // (round 7: VGPR=40, 2000B/pt scratch writes, VALUBusy 3.9%).
  float acc[64];
  #pragma unroll
  for (int c = 0; c < 64; ++c) acc[c] = 0.f;

  for (int k = 0; k < 64; ++k) {
    float pf = fmaxf(fmaf(h0c(f, W0, k), sc0[k], sh0[k]), 0.f);
    const float* wr = W1 + (size_t)k * 128 + CB;
    #pragma unroll
    for (int c = 0; c < 64; ++c) acc[c] = fmaf(pf, wr[c], acc[c]);
  }
  const unsigned int* row = vmax + (size_t)v * 64;
  for (int k = 0; k < 64; ++k) {
    float pf = __uint_as_float(row[k]);
    const float* wr = W1 + (size_t)(64 + k) * 128 + CB;
    #pragma unroll
    for (int c = 0; c < 64; ++c) acc[c] = fmaf(pf, wr[c], acc[c]);
  }

  if (STATS) {
    #pragma unroll
    for (int c = 0; c < 64; ++c) {
      float h = ok ? acc[c] : 0.f;
      float q = h * h;
      #pragma unroll
      for (int m = 1; m < 64; m <<= 1) {
        h += __shfl_xor(h, m, 64);
        q += __shfl_xor(q, m, 64);
      }
      if (ln == 0) { bs[wv][c] = h; bq[wv][c] = q; }
    }
    __syncthreads();
    if (t < 64) {
      atomicAdd(&gs[CB + t], (double)bs[0][t] + bs[1][t] + bs[2][t] + bs[3][t]);
      atomicAdd(&gq[CB + t], (double)bq[0][t] + bq[1][t] + bq[2][t] + bq[3][t]);
    }
  } else if (ok) {
    unsigned int* orow = outp + (size_t)v * 128 + CB;
    #pragma unroll
    for (int c = 0; c < 64; ++c) {
      float val = fmaxf(fmaf(acc[c], sc1[CB + c], sh1[CB + c]), 0.f);
      atomicMax(&orow[c], __float_as_uint(val));   // val >= 0
    }
  }
}

extern "C" void kernel_launch(void* const* d_in, const int* in_sizes, int n_in,
                              void* d_out, int out_size, void* d_ws, size_t ws_size,
                              hipStream_t stream) {
  const float* pts = (const float*)d_in[0];
  const float* W0  = (const float*)d_in[1];
  const float* g0  = (const float*)d_in[2];
  const float* b0  = (const float*)d_in[3];
  const float* W1  = (const float*)d_in[4];
  const float* g1  = (const float*)d_in[5];
  const float* b1  = (const float*)d_in[6];

  char* base = (char*)d_ws;
  double* stats = (double*)base;              // 384 f64
  float*  fold  = (float*)(base + 3072);      // 384 f32
  float*  vcnt  = (float*)(base + 4608);
  float*  vsx   = vcnt + NVOX;
  float*  vsy   = vsx + NVOX;
  float*  vsz   = vsy + NVOX;
  unsigned int* vmax = (unsigned int*)(vsz + NVOX);  // NVOX*64 u32 (72 MB)
  double* s0 = stats,       *q0 = stats + 64;
  double* s1 = stats + 128, *q1 = stats + 256;
  float* sc0 = fold,       *sh0 = fold + 64;
  float* sc1 = fold + 128, *sh1 = fold + 256;

  hipMemsetAsync(stats, 0, 3072, stream);
  hipMemsetAsync(vcnt, 0, (size_t)4 * NVOX * sizeof(float), stream);
  hipMemsetAsync(vmax, 0, (size_t)NVOX * 64 * sizeof(unsigned int), stream);
  hipMemsetAsync(d_out, 0, (size_t)out_size * sizeof(float), stream);

  voxsum<<<NBLK, TPB, 0, stream>>>(pts, vcnt, vsx, vsy, vsz);
  bn0stats<<<NBLK, TPB, 0, stream>>>(pts, vcnt, vsx, vsy, vsz, W0, s0, q0);
  bnfold<<<1, 64, 0, stream>>>(s0, q0, g0, b0, sc0, sh0, 64);
  pf0max<<<NBLK, TPB, 0, stream>>>(pts, vcnt, vsx, vsy, vsz, W0, sc0, sh0, vmax);
  layer1<1, 0><<<NBLK, TPB, 0, stream>>>(pts, vcnt, vsx, vsy, vsz, W0, sc0, sh0,
                                         vmax, W1, s1, q1, nullptr, nullptr, nullptr);
  layer1<1, 64><<<NBLK, TPB, 0, stream>>>(pts, vcnt, vsx, vsy, vsz, W0, sc0, sh0,
                                          vmax, W1, s1, q1, nullptr, nullptr, nullptr);
  bnfold<<<1, 128, 0, stream>>>(s1, q1, g1, b1, sc1, sh1, 128);
  layer1<0, 0><<<NBLK, TPB, 0, stream>>>(pts, vcnt, vsx, vsy, vsz, W0, sc0, sh0,
                                         vmax, W1, nullptr, nullptr, sc1, sh1,
                                         (unsigned int*)d_out);
  layer1<0, 64><<<NBLK, TPB, 0, stream>>>(pts, vcnt, vsx, vsy, vsz, W0, sc0, sh0,
                                          vmax, W1, nullptr, nullptr, sc1, sh1,
                                          (unsigned int*)d_out);
}

// Round 9
// 2857.292 us; speedup vs baseline: 1.7018x; 1.7018x over previous
//
#include <hip/hip_runtime.h>
#include <stdint.h>

#define NPTS 400000
#define NVOX 281600
#define TPB  256
#define NBLK ((NPTS + TPB - 1) / TPB)
#define PPB 8                    // points per block in gemm1
#define GROUPS (NPTS / PPB)      // 50000 exactly
#define SBLK 2000                // stats-pass grid (grid-stride, 25 groups/block)

// XLA-style binning: division folded to multiply-by-reciprocal in f32
// (1/0.2f == 5.0f exactly). DO NOT CHANGE: exactly matches the golden
// (round 6->7 proof).
__device__ __forceinline__ int bin3(const float* __restrict__ pt,
                                    int& bx, int& by, int& bz) {
  float x = pt[1], y = pt[2], z = pt[3];
  bx = (int)fminf(fmaxf(floorf(x * 5.0f), 0.f), 351.f);
  by = (int)fminf(fmaxf(floorf((y + 40.f) * 5.0f), 0.f), 399.f);
  bz = (int)fminf(fmaxf(floorf((z + 3.f) * 0.25f), 0.f), 0.f);
  return (((int)pt[0] + bz) * 400 + by) * 352 + bx;
}

__device__ __forceinline__ int mkfeat(const float* __restrict__ pt,
    const float* __restrict__ vcnt, const float* __restrict__ vsx,
    const float* __restrict__ vsy, const float* __restrict__ vsz,
    float* f) {
  int bx, by, bz;
  int v = bin3(pt, bx, by, bz);
  float x = pt[1], y = pt[2], z = pt[3];
  float n = fmaxf(vcnt[v], 1.f);
  f[0] = x;  f[1] = y;  f[2] = z;  f[3] = pt[4];
  f[4] = x - vsx[v] / n;
  f[5] = y - vsy[v] / n;
  f[6] = z - vsz[v] / n;
  f[7] = x - (0.2f * (float)bx + 0.1f);
  f[8] = y - (0.2f * (float)by - 39.9f);
  f[9] = z - (4.0f * (float)bz - 1.0f);
  return v;
}

__device__ __forceinline__ float h0c(const float* f,
                                     const float* __restrict__ W0, int c) {
  float h = f[0] * W0[c];
  #pragma unroll
  for (int i = 1; i < 10; ++i) h = fmaf(f[i], W0[i * 64 + c], h);
  return h;
}

// ---------------- unchanged prologue kernels (verbatim from passing R7) ---
__global__ __launch_bounds__(256) void voxsum(const float* __restrict__ pts,
    float* __restrict__ vcnt, float* __restrict__ vsx,
    float* __restrict__ vsy, float* __restrict__ vsz) {
  int p = blockIdx.x * TPB + threadIdx.x;
  if (p >= NPTS) return;
  const float* pt = pts + (size_t)p * 5;
  int bx, by, bz;
  int v = bin3(pt, bx, by, bz);
  atomicAdd(&vcnt[v], 1.f);
  atomicAdd(&vsx[v], pt[1]);
  atomicAdd(&vsy[v], pt[2]);
  atomicAdd(&vsz[v], pt[3]);
}

__global__ __launch_bounds__(256) void bn0stats(const float* __restrict__ pts,
    const float* __restrict__ vcnt, const float* __restrict__ vsx,
    const float* __restrict__ vsy, const float* __restrict__ vsz,
    const float* __restrict__ W0,
    double* __restrict__ gs, double* __restrict__ gq) {
  __shared__ float bs[4][64], bq[4][64];
  int t = threadIdx.x, wv = t >> 6, ln = t & 63;
  int p = blockIdx.x * TPB + t;
  bool ok = p < NPTS;
  const float* pt = pts + (size_t)(ok ? p : 0) * 5;
  float f[10];
  mkfeat(pt, vcnt, vsx, vsy, vsz, f);
  for (int c = 0; c < 64; ++c) {
    float h = ok ? h0c(f, W0, c) : 0.f;
    float q = h * h;
    #pragma unroll
    for (int m = 1; m < 64; m <<= 1) {
      h += __shfl_xor(h, m, 64);
      q += __shfl_xor(q, m, 64);
    }
    if (ln == 0) { bs[wv][c] = h; bq[wv][c] = q; }
  }
  __syncthreads();
  if (t < 64) {
    atomicAdd(&gs[t], (double)bs[0][t] + bs[1][t] + bs[2][t] + bs[3][t]);
    atomicAdd(&gq[t], (double)bq[0][t] + bq[1][t] + bq[2][t] + bq[3][t]);
  }
}

__global__ void bnfold(const double* __restrict__ gs, const double* __restrict__ gq,
                       const float* __restrict__ gam, const float* __restrict__ bet,
                       float* __restrict__ sc, float* __restrict__ sh, int C) {
  int c = threadIdx.x;
  if (c >= C) return;
  double mu  = gs[c] / (double)NPTS;
  double var = gq[c] / (double)NPTS - mu * mu;
  double s = (double)gam[c] / sqrt(var + 1e-3);
  sc[c] = (float)s;
  sh[c] = (float)((double)bet[c] - mu * s);
}

__global__ __launch_bounds__(256) void pf0max(const float* __restrict__ pts,
    const float* __restrict__ vcnt, const float* __restrict__ vsx,
    const float* __restrict__ vsy, const float* __restrict__ vsz,
    const float* __restrict__ W0, const float* __restrict__ sc0,
    const float* __restrict__ sh0, unsigned int* __restrict__ vmax) {
  int p = blockIdx.x * TPB + threadIdx.x;
  if (p >= NPTS) return;
  const float* pt = pts + (size_t)p * 5;
  float f[10];
  int v = mkfeat(pt, vcnt, vsx, vsy, vsz, f);
  unsigned int* row = vmax + (size_t)v * 64;
  for (int c = 0; c < 64; ++c) {
    float pf = fmaxf(fmaf(h0c(f, W0, c), sc0[c], sh0[c]), 0.f);
    atomicMax(&row[c], __float_as_uint(pf));
  }
}

// ---------------- layer1 as block-cooperative GEMM ----------------
// Block: 256 threads, PPB=8 points. feats1[8][128] staged in LDS.
// Thread (pl = t>>5, cb = t&31) computes channels cb*4..cb*4+3 for point pl
// with 4 NAMED SCALAR accumulators (no local array => nothing can spill;
// R7/R8 showed acc[64] lands in scratch: VGPR=40, 800MB fake writes).
template <int STATS>
__global__ __launch_bounds__(256) void gemm1(const float* __restrict__ pts,
    const float* __restrict__ vcnt, const float* __restrict__ vsx,
    const float* __restrict__ vsy, const float* __restrict__ vsz,
    const float* __restrict__ W0, const float* __restrict__ sc0,
    const float* __restrict__ sh0, const unsigned int* __restrict__ vmax,
    const float* __restrict__ W1,
    double* __restrict__ gs, double* __restrict__ gq,
    const float* __restrict__ sc1, const float* __restrict__ sh1,
    unsigned int* __restrict__ outp) {
  __shared__ float sf[PPB][12];          // per-point 10 features
  __shared__ int   svid[PPB];
  __shared__ float sfeat[PPB][128];      // feats1 = [pf0 | vmax0]
  __shared__ double ssum[STATS ? PPB * 128 : 1];
  __shared__ double ssq [STATS ? PPB * 128 : 1];

  int t = threadIdx.x;
  int pl = t >> 5, cb = t & 31;

  // per-thread f64 stats partials (named scalars)
  double sd0 = 0, sd1 = 0, sd2 = 0, sd3 = 0;
  double qd0 = 0, qd1 = 0, qd2 = 0, qd3 = 0;

  for (int g = blockIdx.x; g < GROUPS; g += gridDim.x) {
    int pbase = g * PPB;
    // stage per-point features (8 threads)
    if (t < PPB) {
      svid[t] = mkfeat(pts + (size_t)(pbase + t) * 5,
                       vcnt, vsx, vsy, vsz, &sf[t][0]);
    }
    __syncthreads();
    // pf0 (512 items) + vmax gather (512 items), 4 per thread
    for (int idx = t; idx < PPB * 64; idx += TPB) {
      int pt_ = idx >> 6, k = idx & 63;
      float h = sf[pt_][0] * W0[k];
      #pragma unroll
      for (int i = 1; i < 10; ++i) h = fmaf(sf[pt_][i], W0[i * 64 + k], h);
      sfeat[pt_][k] = fmaxf(fmaf(h, sc0[k], sh0[k]), 0.f);
    }
    for (int idx = t; idx < PPB * 64; idx += TPB) {
      int pt_ = idx >> 6, k = idx & 63;
      sfeat[pt_][64 + k] =
          __uint_as_float(vmax[(size_t)svid[pt_] * 64 + k]);
    }
    __syncthreads();

    // GEMM: h1[pl][cb*4..+3] — ascending-k fmaf chain (order == R7)
    float a0 = 0.f, a1 = 0.f, a2 = 0.f, a3 = 0.f;
    for (int k = 0; k < 128; ++k) {
      float pf = sfeat[pl][k];
      float4 w = *reinterpret_cast<const float4*>(W1 + (size_t)k * 128 + cb * 4);
      a0 = fmaf(pf, w.x, a0);
      a1 = fmaf(pf, w.y, a1);
      a2 = fmaf(pf, w.z, a2);
      a3 = fmaf(pf, w.w, a3);
    }

    if (STATS) {
      sd0 += (double)a0; qd0 += (double)a0 * (double)a0;
      sd1 += (double)a1; qd1 += (double)a1 * (double)a1;
      sd2 += (double)a2; qd2 += (double)a2 * (double)a2;
      sd3 += (double)a3; qd3 += (double)a3 * (double)a3;
    } else {
      int c = cb * 4;
      unsigned int* orow = outp + (size_t)svid[pl] * 128 + c;
      float v0 = fmaxf(fmaf(a0, sc1[c + 0], sh1[c + 0]), 0.f);
      float v1 = fmaxf(fmaf(a1, sc1[c + 1], sh1[c + 1]), 0.f);
      float v2 = fmaxf(fmaf(a2, sc1[c + 2], sh1[c + 2]), 0.f);
      float v3 = fmaxf(fmaf(a3, sc1[c + 3], sh1[c + 3]), 0.f);
      atomicMax(&orow[0], __float_as_uint(v0));
      atomicMax(&orow[1], __float_as_uint(v1));
      atomicMax(&orow[2], __float_as_uint(v2));
      atomicMax(&orow[3], __float_as_uint(v3));
    }
    __syncthreads();   // protect LDS before next group's staging
  }

  if (STATS) {
    ssum[pl * 128 + cb * 4 + 0] = sd0;  ssq[pl * 128 + cb * 4 + 0] = qd0;
    ssum[pl * 128 + cb * 4 + 1] = sd1;  ssq[pl * 128 + cb * 4 + 1] = qd1;
    ssum[pl * 128 + cb * 4 + 2] = sd2;  ssq[pl * 128 + cb * 4 + 2] = qd2;
    ssum[pl * 128 + cb * 4 + 3] = sd3;  ssq[pl * 128 + cb * 4 + 3] = qd3;
    __syncthreads();
    if (t < 128) {
      double S = 0, Q = 0;
      #pragma unroll
      for (int j = 0; j < PPB; ++j) {
        S += ssum[j * 128 + t];
        Q += ssq [j * 128 + t];
      }
      atomicAdd(&gs[t], S);
      atomicAdd(&gq[t], Q);
    }
  }
}

extern "C" void kernel_launch(void* const* d_in, const int* in_sizes, int n_in,
                              void* d_out, int out_size, void* d_ws, size_t ws_size,
                              hipStream_t stream) {
  const float* pts = (const float*)d_in[0];
  const float* W0  = (const float*)d_in[1];
  const float* g0  = (const float*)d_in[2];
  const float* b0  = (const float*)d_in[3];
  const float* W1  = (const float*)d_in[4];
  const float* g1  = (const float*)d_in[5];
  const float* b1  = (const float*)d_in[6];

  char* base = (char*)d_ws;
  double* stats = (double*)base;              // 384 f64
  float*  fold  = (float*)(base + 3072);      // 384 f32
  float*  vcnt  = (float*)(base + 4608);
  float*  vsx   = vcnt + NVOX;
  float*  vsy   = vsx + NVOX;
  float*  vsz   = vsy + NVOX;
  unsigned int* vmax = (unsigned int*)(vsz + NVOX);  // NVOX*64 u32 (72 MB)
  double* s0 = stats,       *q0 = stats + 64;
  double* s1 = stats + 128, *q1 = stats + 256;
  float* sc0 = fold,       *sh0 = fold + 64;
  float* sc1 = fold + 128, *sh1 = fold + 256;

  hipMemsetAsync(stats, 0, 3072, stream);
  hipMemsetAsync(vcnt, 0, (size_t)4 * NVOX * sizeof(float), stream);
  hipMemsetAsync(vmax, 0, (size_t)NVOX * 64 * sizeof(unsigned int), stream);
  hipMemsetAsync(d_out, 0, (size_t)out_size * sizeof(float), stream);

  voxsum<<<NBLK, TPB, 0, stream>>>(pts, vcnt, vsx, vsy, vsz);
  bn0stats<<<NBLK, TPB, 0, stream>>>(pts, vcnt, vsx, vsy, vsz, W0, s0, q0);
  bnfold<<<1, 64, 0, stream>>>(s0, q0, g0, b0, sc0, sh0, 64);
  pf0max<<<NBLK, TPB, 0, stream>>>(pts, vcnt, vsx, vsy, vsz, W0, sc0, sh0, vmax);
  gemm1<1><<<SBLK, TPB, 0, stream>>>(pts, vcnt, vsx, vsy, vsz, W0, sc0, sh0,
                                     vmax, W1, s1, q1, nullptr, nullptr, nullptr);
  bnfold<<<1, 128, 0, stream>>>(s1, q1, g1, b1, sc1, sh1, 128);
  gemm1<0><<<GROUPS, TPB, 0, stream>>>(pts, vcnt, vsx, vsy, vsz, W0, sc0, sh0,
                                       vmax, W1, nullptr, nullptr, sc1, sh1,
                                       (unsigned int*)d_out);
}

// Round 10
// 2454.234 us; speedup vs baseline: 1.9813x; 1.1642x over previous
//
#include <hip/hip_runtime.h>
#include <stdint.h>

#define NPTS 400000
#define NVOX 281600
#define TPB  256
#define NBLK ((NPTS + TPB - 1) / TPB)
#define PPB 8
#define GROUPS (NPTS / PPB)
#define SBLK 2000
#define SCANB (NVOX / 256)     // 1100 exact

// XLA-style binning: division folded to multiply-by-reciprocal in f32.
// DO NOT CHANGE: exactly matches the golden (round 6->7 proof).
__device__ __forceinline__ int bin3(const float* __restrict__ pt,
                                    int& bx, int& by, int& bz) {
  float x = pt[1], y = pt[2], z = pt[3];
  bx = (int)fminf(fmaxf(floorf(x * 5.0f), 0.f), 351.f);
  by = (int)fminf(fmaxf(floorf((y + 40.f) * 5.0f), 0.f), 399.f);
  bz = (int)fminf(fmaxf(floorf((z + 3.f) * 0.25f), 0.f), 0.f);
  return (((int)pt[0] + bz) * 400 + by) * 352 + bx;
}

__device__ __forceinline__ int mkfeat(const float* __restrict__ pt,
    const float* __restrict__ vcnt, const float* __restrict__ vsx,
    const float* __restrict__ vsy, const float* __restrict__ vsz,
    float* f) {
  int bx, by, bz;
  int v = bin3(pt, bx, by, bz);
  float x = pt[1], y = pt[2], z = pt[3];
  float n = fmaxf(vcnt[v], 1.f);
  f[0] = x;  f[1] = y;  f[2] = z;  f[3] = pt[4];
  f[4] = x - vsx[v] / n;
  f[5] = y - vsy[v] / n;
  f[6] = z - vsz[v] / n;
  f[7] = x - (0.2f * (float)bx + 0.1f);
  f[8] = y - (0.2f * (float)by - 39.9f);
  f[9] = z - (4.0f * (float)bz - 1.0f);
  return v;
}

// same features, voxel-centric (bx,by decoded from v; identical expressions)
__device__ __forceinline__ void mkfeat_vox(const float* __restrict__ pt,
    float mx, float my, float mz, int bx, int by, float* f) {
  float x = pt[1], y = pt[2], z = pt[3];
  f[0] = x;  f[1] = y;  f[2] = z;  f[3] = pt[4];
  f[4] = x - mx;
  f[5] = y - my;
  f[6] = z - mz;
  f[7] = x - (0.2f * (float)bx + 0.1f);
  f[8] = y - (0.2f * (float)by - 39.9f);
  f[9] = z - (4.0f * (float)0 - 1.0f);
}

__device__ __forceinline__ float h0c(const float* f,
                                     const float* __restrict__ W0, int c) {
  float h = f[0] * W0[c];
  #pragma unroll
  for (int i = 1; i < 10; ++i) h = fmaf(f[i], W0[i * 64 + c], h);
  return h;
}

// ---------------- point-centric prologue (verbatim, proven) ----------------
__global__ __launch_bounds__(256) void voxsum(const float* __restrict__ pts,
    float* __restrict__ vcnt, float* __restrict__ vsx,
    float* __restrict__ vsy, float* __restrict__ vsz) {
  int p = blockIdx.x * TPB + threadIdx.x;
  if (p >= NPTS) return;
  const float* pt = pts + (size_t)p * 5;
  int bx, by, bz;
  int v = bin3(pt, bx, by, bz);
  atomicAdd(&vcnt[v], 1.f);
  atomicAdd(&vsx[v], pt[1]);
  atomicAdd(&vsy[v], pt[2]);
  atomicAdd(&vsz[v], pt[3]);
}

__global__ __launch_bounds__(256) void bn0stats(const float* __restrict__ pts,
    const float* __restrict__ vcnt, const float* __restrict__ vsx,
    const float* __restrict__ vsy, const float* __restrict__ vsz,
    const float* __restrict__ W0,
    double* __restrict__ gs, double* __restrict__ gq) {
  __shared__ float bs[4][64], bq[4][64];
  int t = threadIdx.x, wv = t >> 6, ln = t & 63;
  int p = blockIdx.x * TPB + t;
  bool ok = p < NPTS;
  const float* pt = pts + (size_t)(ok ? p : 0) * 5;
  float f[10];
  mkfeat(pt, vcnt, vsx, vsy, vsz, f);
  for (int c = 0; c < 64; ++c) {
    float h = ok ? h0c(f, W0, c) : 0.f;
    float q = h * h;
    #pragma unroll
    for (int m = 1; m < 64; m <<= 1) {
      h += __shfl_xor(h, m, 64);
      q += __shfl_xor(q, m, 64);
    }
    if (ln == 0) { bs[wv][c] = h; bq[wv][c] = q; }
  }
  __syncthreads();
  if (t < 64) {
    atomicAdd(&gs[t], (double)bs[0][t] + bs[1][t] + bs[2][t] + bs[3][t]);
    atomicAdd(&gq[t], (double)bq[0][t] + bq[1][t] + bq[2][t] + bq[3][t]);
  }
}

__global__ void bnfold(const double* __restrict__ gs, const double* __restrict__ gq,
                       const float* __restrict__ gam, const float* __restrict__ bet,
                       float* __restrict__ sc, float* __restrict__ sh, int C) {
  int c = threadIdx.x;
  if (c >= C) return;
  double mu  = gs[c] / (double)NPTS;
  double var = gq[c] / (double)NPTS - mu * mu;
  double s = (double)gam[c] / sqrt(var + 1e-3);
  sc[c] = (float)s;
  sh[c] = (float)((double)bet[c] - mu * s);
}

// ---------------- counting sort: scan + scatter ----------------
__global__ __launch_bounds__(256) void scan1(const float* __restrict__ vcnt,
    unsigned int* __restrict__ voxloc, unsigned int* __restrict__ bsum) {
  __shared__ unsigned int s[256];
  int t = threadIdx.x;
  int i = blockIdx.x * 256 + t;
  unsigned int val = (unsigned int)vcnt[i];
  s[t] = val;
  __syncthreads();
  for (int off = 1; off < 256; off <<= 1) {
    unsigned int add = (t >= off) ? s[t - off] : 0u;
    __syncthreads();
    s[t] += add;
    __syncthreads();
  }
  voxloc[i] = s[t] - val;               // exclusive within block
  if (t == 255) bsum[blockIdx.x] = s[t];
}

__global__ void scan2(const unsigned int* __restrict__ bsum,
                      unsigned int* __restrict__ bexc) {
  if (threadIdx.x != 0) return;
  unsigned int run = 0;
  for (int b = 0; b < SCANB; ++b) { bexc[b] = run; run += bsum[b]; }
}

__global__ __launch_bounds__(256) void scatter(const float* __restrict__ pts,
    const unsigned int* __restrict__ voxloc, const unsigned int* __restrict__ bexc,
    unsigned int* __restrict__ cursor, unsigned int* __restrict__ plist) {
  int p = blockIdx.x * TPB + threadIdx.x;
  if (p >= NPTS) return;
  int bx, by, bz;
  int v = bin3(pts + (size_t)p * 5, bx, by, bz);
  unsigned int pos = voxloc[v] + bexc[v >> 8] + atomicAdd(&cursor[v], 1u);
  plist[pos] = (unsigned int)p;
}

// ---------------- voxel-centric vmax0 (no atomics) ----------------
__global__ __launch_bounds__(64) void vmax0_vox(const float* __restrict__ pts,
    const float* __restrict__ vcnt, const float* __restrict__ vsx,
    const float* __restrict__ vsy, const float* __restrict__ vsz,
    const unsigned int* __restrict__ voxloc, const unsigned int* __restrict__ bexc,
    const unsigned int* __restrict__ plist,
    const float* __restrict__ W0, const float* __restrict__ sc0,
    const float* __restrict__ sh0, float* __restrict__ vmax) {
  int v = blockIdx.x;
  int n = (int)vcnt[v];
  if (n == 0) return;                 // vmax row stays memset-0
  int c = threadIdx.x;
  unsigned int base = voxloc[v] + bexc[v >> 8];
  float fn = fmaxf(vcnt[v], 1.f);
  float mx = vsx[v] / fn, my = vsy[v] / fn, mz = vsz[v] / fn;
  int bx = v % 352, by = (v / 352) % 400;
  float m = 0.f;
  for (int i = 0; i < n; ++i) {
    const float* pt = pts + (size_t)plist[base + i] * 5;
    float f[10];
    mkfeat_vox(pt, mx, my, mz, bx, by, f);
    float pf = fmaxf(fmaf(h0c(f, W0, c), sc0[c], sh0[c]), 0.f);
    m = fmaxf(m, pf);
  }
  vmax[(size_t)v * 64 + c] = m;
}

// ---------------- stats pass (verbatim from R9, atomic-free) ----------------
__global__ __launch_bounds__(256) void gemm1s(const float* __restrict__ pts,
    const float* __restrict__ vcnt, const float* __restrict__ vsx,
    const float* __restrict__ vsy, const float* __restrict__ vsz,
    const float* __restrict__ W0, const float* __restrict__ sc0,
    const float* __restrict__ sh0, const float* __restrict__ vmax,
    const float* __restrict__ W1,
    double* __restrict__ gs, double* __restrict__ gq) {
  __shared__ float sf[PPB][12];
  __shared__ int   svid[PPB];
  __shared__ float sfeat[PPB][128];
  __shared__ double ssum[PPB * 128];
  __shared__ double ssq [PPB * 128];

  int t = threadIdx.x;
  int pl = t >> 5, cb = t & 31;
  double sd0 = 0, sd1 = 0, sd2 = 0, sd3 = 0;
  double qd0 = 0, qd1 = 0, qd2 = 0, qd3 = 0;

  for (int g = blockIdx.x; g < GROUPS; g += gridDim.x) {
    int pbase = g * PPB;
    if (t < PPB) {
      svid[t] = mkfeat(pts + (size_t)(pbase + t) * 5,
                       vcnt, vsx, vsy, vsz, &sf[t][0]);
    }
    __syncthreads();
    for (int idx = t; idx < PPB * 64; idx += TPB) {
      int pt_ = idx >> 6, k = idx & 63;
      float h = sf[pt_][0] * W0[k];
      #pragma unroll
      for (int i = 1; i < 10; ++i) h = fmaf(sf[pt_][i], W0[i * 64 + k], h);
      sfeat[pt_][k] = fmaxf(fmaf(h, sc0[k], sh0[k]), 0.f);
    }
    for (int idx = t; idx < PPB * 64; idx += TPB) {
      int pt_ = idx >> 6, k = idx & 63;
      sfeat[pt_][64 + k] = vmax[(size_t)svid[pt_] * 64 + k];
    }
    __syncthreads();

    float a0 = 0.f, a1 = 0.f, a2 = 0.f, a3 = 0.f;
    for (int k = 0; k < 128; ++k) {
      float pf = sfeat[pl][k];
      float4 w = *reinterpret_cast<const float4*>(W1 + (size_t)k * 128 + cb * 4);
      a0 = fmaf(pf, w.x, a0);
      a1 = fmaf(pf, w.y, a1);
      a2 = fmaf(pf, w.z, a2);
      a3 = fmaf(pf, w.w, a3);
    }
    sd0 += (double)a0; qd0 += (double)a0 * (double)a0;
    sd1 += (double)a1; qd1 += (double)a1 * (double)a1;
    sd2 += (double)a2; qd2 += (double)a2 * (double)a2;
    sd3 += (double)a3; qd3 += (double)a3 * (double)a3;
    __syncthreads();
  }

  ssum[pl * 128 + cb * 4 + 0] = sd0;  ssq[pl * 128 + cb * 4 + 0] = qd0;
  ssum[pl * 128 + cb * 4 + 1] = sd1;  ssq[pl * 128 + cb * 4 + 1] = qd1;
  ssum[pl * 128 + cb * 4 + 2] = sd2;  ssq[pl * 128 + cb * 4 + 2] = qd2;
  ssum[pl * 128 + cb * 4 + 3] = sd3;  ssq[pl * 128 + cb * 4 + 3] = qd3;
  __syncthreads();
  if (t < 128) {
    double S = 0, Q = 0;
    #pragma unroll
    for (int j = 0; j < PPB; ++j) { S += ssum[j * 128 + t]; Q += ssq[j * 128 + t]; }
    atomicAdd(&gs[t], S);
    atomicAdd(&gq[t], Q);
  }
}

// ---------------- voxel-centric final pass (no atomics) ----------------
__global__ __launch_bounds__(64) void final_vox(const float* __restrict__ pts,
    const float* __restrict__ vcnt, const float* __restrict__ vsx,
    const float* __restrict__ vsy, const float* __restrict__ vsz,
    const unsigned int* __restrict__ voxloc, const unsigned int* __restrict__ bexc,
    const unsigned int* __restrict__ plist,
    const float* __restrict__ W0, const float* __restrict__ sc0,
    const float* __restrict__ sh0, const float* __restrict__ vmax,
    const float* __restrict__ W1, const float* __restrict__ sc1,
    const float* __restrict__ sh1, float* __restrict__ outp) {
  int v = blockIdx.x;
  int n = (int)vcnt[v];
  if (n == 0) return;                 // out row stays memset-0
  int c = threadIdx.x;                // covers channels c and 64+c
  __shared__ float feat[128];
  feat[64 + c] = vmax[(size_t)v * 64 + c];

  unsigned int base = voxloc[v] + bexc[v >> 8];
  float fn = fmaxf(vcnt[v], 1.f);
  float mx = vsx[v] / fn, my = vsy[v] / fn, mz = vsz[v] / fn;
  int bx = v % 352, by = (v / 352) % 400;

  float m0 = 0.f, m1 = 0.f;
  for (int i = 0; i < n; ++i) {
    const float* pt = pts + (size_t)plist[base + i] * 5;
    float f[10];
    mkfeat_vox(pt, mx, my, mz, bx, by, f);
    feat[c] = fmaxf(fmaf(h0c(f, W0, c), sc0[c], sh0[c]), 0.f);
    __syncthreads();
    float a0 = 0.f, a1 = 0.f;
    #pragma unroll
    for (int k4 = 0; k4 < 32; ++k4) {
      float4 fv = reinterpret_cast<const float4*>(feat)[k4];
      a0 = fmaf(fv.x, W1[(k4 * 4 + 0) * 128 + c], a0);
      a1 = fmaf(fv.x, W1[(k4 * 4 + 0) * 128 + 64 + c], a1);
      a0 = fmaf(fv.y, W1[(k4 * 4 + 1) * 128 + c], a0);
      a1 = fmaf(fv.y, W1[(k4 * 4 + 1) * 128 + 64 + c], a1);
      a0 = fmaf(fv.z, W1[(k4 * 4 + 2) * 128 + c], a0);
      a1 = fmaf(fv.z, W1[(k4 * 4 + 2) * 128 + 64 + c], a1);
      a0 = fmaf(fv.w, W1[(k4 * 4 + 3) * 128 + c], a0);
      a1 = fmaf(fv.w, W1[(k4 * 4 + 3) * 128 + 64 + c], a1);
    }
    __syncthreads();
    m0 = fmaxf(m0, fmaxf(fmaf(a0, sc1[c],      sh1[c]),      0.f));
    m1 = fmaxf(m1, fmaxf(fmaf(a1, sc1[64 + c], sh1[64 + c]), 0.f));
  }
  outp[(size_t)v * 128 + c]      = m0;
  outp[(size_t)v * 128 + 64 + c] = m1;
}

extern "C" void kernel_launch(void* const* d_in, const int* in_sizes, int n_in,
                              void* d_out, int out_size, void* d_ws, size_t ws_size,
                              hipStream_t stream) {
  const float* pts = (const float*)d_in[0];
  const float* W0  = (const float*)d_in[1];
  const float* g0  = (const float*)d_in[2];
  const float* b0  = (const float*)d_in[3];
  const float* W1  = (const float*)d_in[4];
  const float* g1  = (const float*)d_in[5];
  const float* b1  = (const float*)d_in[6];

  char* base = (char*)d_ws;
  double* stats = (double*)base;                       // 384 f64
  float*  fold  = (float*)(base + 3072);               // 384 f32
  float*  vcnt  = (float*)(base + 4608);
  float*  vsx   = vcnt + NVOX;
  float*  vsy   = vsx + NVOX;
  float*  vsz   = vsy + NVOX;
  float*  vmax  = vsz + NVOX;                          // NVOX*64 f32 (72MB)
  unsigned int* voxloc = (unsigned int*)(vmax + (size_t)NVOX * 64);
  unsigned int* cursor = voxloc + NVOX;
  unsigned int* plist  = cursor + NVOX;
  unsigned int* bsum   = plist + NPTS;
  unsigned int* bexc   = bsum + SCANB;

  double* s0 = stats,       *q0 = stats + 64;
  double* s1 = stats + 128, *q1 = stats + 256;
  float* sc0 = fold,       *sh0 = fold + 64;
  float* sc1 = fold + 128, *sh1 = fold + 256;

  hipMemsetAsync(stats, 0, 3072, stream);
  hipMemsetAsync(vcnt, 0, (size_t)4 * NVOX * sizeof(float), stream);
  hipMemsetAsync(vmax, 0, (size_t)NVOX * 64 * sizeof(float), stream);
  hipMemsetAsync(cursor, 0, (size_t)NVOX * sizeof(unsigned int), stream);
  hipMemsetAsync(d_out, 0, (size_t)out_size * sizeof(float), stream);

  voxsum<<<NBLK, TPB, 0, stream>>>(pts, vcnt, vsx, vsy, vsz);
  scan1<<<SCANB, 256, 0, stream>>>(vcnt, voxloc, bsum);
  scan2<<<1, 64, 0, stream>>>(bsum, bexc);
  scatter<<<NBLK, TPB, 0, stream>>>(pts, voxloc, bexc, cursor, plist);
  bn0stats<<<NBLK, TPB, 0, stream>>>(pts, vcnt, vsx, vsy, vsz, W0, s0, q0);
  bnfold<<<1, 64, 0, stream>>>(s0, q0, g0, b0, sc0, sh0, 64);
  vmax0_vox<<<NVOX, 64, 0, stream>>>(pts, vcnt, vsx, vsy, vsz, voxloc, bexc,
                                     plist, W0, sc0, sh0, vmax);
  gemm1s<<<SBLK, TPB, 0, stream>>>(pts, vcnt, vsx, vsy, vsz, W0, sc0, sh0,
                                   vmax, W1, s1, q1);
  bnfold<<<1, 128, 0, stream>>>(s1, q1, g1, b1, sc1, sh1, 128);
  final_vox<<<NVOX, 64, 0, stream>>>(pts, vcnt, vsx, vsy, vsz, voxloc, bexc,
                                     plist, W0, sc0, sh0, vmax, W1, sc1, sh1,
                                     (float*)d_out);
}

// Round 11
// 1854.994 us; speedup vs baseline: 2.6214x; 1.3230x over previous
//
#include <hip/hip_runtime.h>
#include <stdint.h>

#define NPTS 400000
#define NVOX 281600
#define TPB  256
#define NBLK ((NPTS + TPB - 1) / TPB)
#define PPB 8
#define GROUPS (NPTS / PPB)
#define SBLK 2000
#define SCANB (NVOX / 256)       // 1100 exact
#define STRETCH 64
#define FBLK (NPTS / STRETCH)    // 6250 exact

// XLA-style binning: division folded to multiply-by-reciprocal in f32.
// DO NOT CHANGE: exactly matches the golden (round 6->7 proof).
__device__ __forceinline__ int bin3(const float* __restrict__ pt,
                                    int& bx, int& by, int& bz) {
  float x = pt[1], y = pt[2], z = pt[3];
  bx = (int)fminf(fmaxf(floorf(x * 5.0f), 0.f), 351.f);
  by = (int)fminf(fmaxf(floorf((y + 40.f) * 5.0f), 0.f), 399.f);
  bz = (int)fminf(fmaxf(floorf((z + 3.f) * 0.25f), 0.f), 0.f);
  return (((int)pt[0] + bz) * 400 + by) * 352 + bx;
}

__device__ __forceinline__ int mkfeat(const float* __restrict__ pt,
    const float* __restrict__ vcnt, const float* __restrict__ vsx,
    const float* __restrict__ vsy, const float* __restrict__ vsz,
    float* f) {
  int bx, by, bz;
  int v = bin3(pt, bx, by, bz);
  float x = pt[1], y = pt[2], z = pt[3];
  float n = fmaxf(vcnt[v], 1.f);
  f[0] = x;  f[1] = y;  f[2] = z;  f[3] = pt[4];
  f[4] = x - vsx[v] / n;
  f[5] = y - vsy[v] / n;
  f[6] = z - vsz[v] / n;
  f[7] = x - (0.2f * (float)bx + 0.1f);
  f[8] = y - (0.2f * (float)by - 39.9f);
  f[9] = z - (4.0f * (float)bz - 1.0f);
  return v;
}

// voxel-centric features (bx,by decoded from v; identical expressions)
__device__ __forceinline__ void mkfeat_vox(const float* __restrict__ pt,
    float mx, float my, float mz, int bx, int by, float* f) {
  float x = pt[1], y = pt[2], z = pt[3];
  f[0] = x;  f[1] = y;  f[2] = z;  f[3] = pt[4];
  f[4] = x - mx;
  f[5] = y - my;
  f[6] = z - mz;
  f[7] = x - (0.2f * (float)bx + 0.1f);
  f[8] = y - (0.2f * (float)by - 39.9f);
  f[9] = z - (4.0f * (float)0 - 1.0f);
}

__device__ __forceinline__ float h0c(const float* f,
                                     const float* __restrict__ W0, int c) {
  float h = f[0] * W0[c];
  #pragma unroll
  for (int i = 1; i < 10; ++i) h = fmaf(f[i], W0[i * 64 + c], h);
  return h;
}

// ---------------- prologue (verbatim, proven) ----------------
__global__ __launch_bounds__(256) void voxsum(const float* __restrict__ pts,
    float* __restrict__ vcnt, float* __restrict__ vsx,
    float* __restrict__ vsy, float* __restrict__ vsz) {
  int p = blockIdx.x * TPB + threadIdx.x;
  if (p >= NPTS) return;
  const float* pt = pts + (size_t)p * 5;
  int bx, by, bz;
  int v = bin3(pt, bx, by, bz);
  atomicAdd(&vcnt[v], 1.f);
  atomicAdd(&vsx[v], pt[1]);
  atomicAdd(&vsy[v], pt[2]);
  atomicAdd(&vsz[v], pt[3]);
}

__global__ __launch_bounds__(256) void bn0stats(const float* __restrict__ pts,
    const float* __restrict__ vcnt, const float* __restrict__ vsx,
    const float* __restrict__ vsy, const float* __restrict__ vsz,
    const float* __restrict__ W0,
    double* __restrict__ gs, double* __restrict__ gq) {
  __shared__ float bs[4][64], bq[4][64];
  int t = threadIdx.x, wv = t >> 6, ln = t & 63;
  int p = blockIdx.x * TPB + t;
  bool ok = p < NPTS;
  const float* pt = pts + (size_t)(ok ? p : 0) * 5;
  float f[10];
  mkfeat(pt, vcnt, vsx, vsy, vsz, f);
  for (int c = 0; c < 64; ++c) {
    float h = ok ? h0c(f, W0, c) : 0.f;
    float q = h * h;
    #pragma unroll
    for (int m = 1; m < 64; m <<= 1) {
      h += __shfl_xor(h, m, 64);
      q += __shfl_xor(q, m, 64);
    }
    if (ln == 0) { bs[wv][c] = h; bq[wv][c] = q; }
  }
  __syncthreads();
  if (t < 64) {
    atomicAdd(&gs[t], (double)bs[0][t] + bs[1][t] + bs[2][t] + bs[3][t]);
    atomicAdd(&gq[t], (double)bq[0][t] + bq[1][t] + bq[2][t] + bq[3][t]);
  }
}

__global__ void bnfold(const double* __restrict__ gs, const double* __restrict__ gq,
                       const float* __restrict__ gam, const float* __restrict__ bet,
                       float* __restrict__ sc, float* __restrict__ sh, int C) {
  int c = threadIdx.x;
  if (c >= C) return;
  double mu  = gs[c] / (double)NPTS;
  double var = gq[c] / (double)NPTS - mu * mu;
  double s = (double)gam[c] / sqrt(var + 1e-3);
  sc[c] = (float)s;
  sh[c] = (float)((double)bet[c] - mu * s);
}

// ---------------- counting sort ----------------
__global__ __launch_bounds__(256) void scan1(const float* __restrict__ vcnt,
    unsigned int* __restrict__ voxloc, unsigned int* __restrict__ bsum) {
  __shared__ unsigned int s[256];
  int t = threadIdx.x;
  int i = blockIdx.x * 256 + t;
  unsigned int val = (unsigned int)vcnt[i];
  s[t] = val;
  __syncthreads();
  for (int off = 1; off < 256; off <<= 1) {
    unsigned int add = (t >= off) ? s[t - off] : 0u;
    __syncthreads();
    s[t] += add;
    __syncthreads();
  }
  voxloc[i] = s[t] - val;
  if (t == 255) bsum[blockIdx.x] = s[t];
}

__global__ void scan2(const unsigned int* __restrict__ bsum,
                      unsigned int* __restrict__ bexc) {
  if (threadIdx.x != 0) return;
  unsigned int run = 0;
  for (int b = 0; b < SCANB; ++b) { bexc[b] = run; run += bsum[b]; }
}

__global__ __launch_bounds__(256) void scatter(const float* __restrict__ pts,
    const unsigned int* __restrict__ voxloc, const unsigned int* __restrict__ bexc,
    unsigned int* __restrict__ cursor, unsigned int* __restrict__ plist) {
  int p = blockIdx.x * TPB + threadIdx.x;
  if (p >= NPTS) return;
  int bx, by, bz;
  int v = bin3(pts + (size_t)p * 5, bx, by, bz);
  unsigned int pos = voxloc[v] + bexc[v >> 8] + atomicAdd(&cursor[v], 1u);
  plist[pos] = (unsigned int)p;
}

// ---------------- voxel-centric vmax0 (no atomics) ----------------
__global__ __launch_bounds__(64) void vmax0_vox(const float* __restrict__ pts,
    const float* __restrict__ vcnt, const float* __restrict__ vsx,
    const float* __restrict__ vsy, const float* __restrict__ vsz,
    const unsigned int* __restrict__ voxloc, const unsigned int* __restrict__ bexc,
    const unsigned int* __restrict__ plist,
    const float* __restrict__ W0, const float* __restrict__ sc0,
    const float* __restrict__ sh0, float* __restrict__ vmax) {
  int v = blockIdx.x;
  int n = (int)vcnt[v];
  if (n == 0) return;
  int c = threadIdx.x;
  unsigned int base = voxloc[v] + bexc[v >> 8];
  float fn = fmaxf(vcnt[v], 1.f);
  float mx = vsx[v] / fn, my = vsy[v] / fn, mz = vsz[v] / fn;
  int bx = v % 352, by = (v / 352) % 400;
  float m = 0.f;
  for (int i = 0; i < n; ++i) {
    const float* pt = pts + (size_t)plist[base + i] * 5;
    float f[10];
    mkfeat_vox(pt, mx, my, mz, bx, by, f);
    float pf = fmaxf(fmaf(h0c(f, W0, c), sc0[c], sh0[c]), 0.f);
    m = fmaxf(m, pf);
  }
  vmax[(size_t)v * 64 + c] = m;
}

// ---------------- stats pass (verbatim, atomic-free) ----------------
__global__ __launch_bounds__(256) void gemm1s(const float* __restrict__ pts,
    const float* __restrict__ vcnt, const float* __restrict__ vsx,
    const float* __restrict__ vsy, const float* __restrict__ vsz,
    const float* __restrict__ W0, const float* __restrict__ sc0,
    const float* __restrict__ sh0, const float* __restrict__ vmax,
    const float* __restrict__ W1,
    double* __restrict__ gs, double* __restrict__ gq) {
  __shared__ float sf[PPB][12];
  __shared__ int   svid[PPB];
  __shared__ float sfeat[PPB][128];
  __shared__ double ssum[PPB * 128];
  __shared__ double ssq [PPB * 128];

  int t = threadIdx.x;
  int pl = t >> 5, cb = t & 31;
  double sd0 = 0, sd1 = 0, sd2 = 0, sd3 = 0;
  double qd0 = 0, qd1 = 0, qd2 = 0, qd3 = 0;

  for (int g = blockIdx.x; g < GROUPS; g += gridDim.x) {
    int pbase = g * PPB;
    if (t < PPB) {
      svid[t] = mkfeat(pts + (size_t)(pbase + t) * 5,
                       vcnt, vsx, vsy, vsz, &sf[t][0]);
    }
    __syncthreads();
    for (int idx = t; idx < PPB * 64; idx += TPB) {
      int pt_ = idx >> 6, k = idx & 63;
      float h = sf[pt_][0] * W0[k];
      #pragma unroll
      for (int i = 1; i < 10; ++i) h = fmaf(sf[pt_][i], W0[i * 64 + k], h);
      sfeat[pt_][k] = fmaxf(fmaf(h, sc0[k], sh0[k]), 0.f);
    }
    for (int idx = t; idx < PPB * 64; idx += TPB) {
      int pt_ = idx >> 6, k = idx & 63;
      sfeat[pt_][64 + k] = vmax[(size_t)svid[pt_] * 64 + k];
    }
    __syncthreads();

    float a0 = 0.f, a1 = 0.f, a2 = 0.f, a3 = 0.f;
    for (int k = 0; k < 128; ++k) {
      float pf = sfeat[pl][k];
      float4 w = *reinterpret_cast<const float4*>(W1 + (size_t)k * 128 + cb * 4);
      a0 = fmaf(pf, w.x, a0);
      a1 = fmaf(pf, w.y, a1);
      a2 = fmaf(pf, w.z, a2);
      a3 = fmaf(pf, w.w, a3);
    }
    sd0 += (double)a0; qd0 += (double)a0 * (double)a0;
    sd1 += (double)a1; qd1 += (double)a1 * (double)a1;
    sd2 += (double)a2; qd2 += (double)a2 * (double)a2;
    sd3 += (double)a3; qd3 += (double)a3 * (double)a3;
    __syncthreads();
  }

  ssum[pl * 128 + cb * 4 + 0] = sd0;  ssq[pl * 128 + cb * 4 + 0] = qd0;
  ssum[pl * 128 + cb * 4 + 1] = sd1;  ssq[pl * 128 + cb * 4 + 1] = qd1;
  ssum[pl * 128 + cb * 4 + 2] = sd2;  ssq[pl * 128 + cb * 4 + 2] = qd2;
  ssum[pl * 128 + cb * 4 + 3] = sd3;  ssq[pl * 128 + cb * 4 + 3] = qd3;
  __syncthreads();
  if (t < 128) {
    double S = 0, Q = 0;
    #pragma unroll
    for (int j = 0; j < PPB; ++j) { S += ssum[j * 128 + t]; Q += ssq[j * 128 + t]; }
    atomicAdd(&gs[t], S);
    atomicAdd(&gq[t], Q);
  }
}

// ---------------- final pass: sorted stretches + segmented max ----------------
// Block owns plist[sbeg, sbeg+64). Chunks of 8 points: gemm1-style GEMM
// (named accumulators) -> p1[8][128] in LDS -> 128 channel-threads run a
// segmented max over the voxel-sorted run. Voxels fully inside the stretch:
// plain store (single writer). Straddling voxels (<=2 per block): atomicMax.
__global__ __launch_bounds__(256) void final_sorted(const float* __restrict__ pts,
    const float* __restrict__ vcnt, const float* __restrict__ vsx,
    const float* __restrict__ vsy, const float* __restrict__ vsz,
    const unsigned int* __restrict__ voxloc, const unsigned int* __restrict__ bexc,
    const unsigned int* __restrict__ plist,
    const float* __restrict__ W0, const float* __restrict__ sc0,
    const float* __restrict__ sh0, const float* __restrict__ vmax,
    const float* __restrict__ W1, const float* __restrict__ sc1,
    const float* __restrict__ sh1, float* __restrict__ outp) {
  __shared__ float sf[PPB][12];
  __shared__ int   svid[PPB];
  __shared__ float sfeat[PPB][128];
  __shared__ float p1[PPB][128];

  int t = threadIdx.x;
  int pl = t >> 5, cb = t & 31;
  unsigned int sbeg = blockIdx.x * STRETCH;

  int   curv = -1;     // per-channel running segment state (t<128)
  float curm = 0.f;

  for (int chunk = 0; chunk < STRETCH / PPB; ++chunk) {
    unsigned int pbase = sbeg + chunk * PPB;
    if (t < PPB) {
      unsigned int pidx = plist[pbase + t];
      svid[t] = mkfeat(pts + (size_t)pidx * 5, vcnt, vsx, vsy, vsz, &sf[t][0]);
    }
    __syncthreads();
    for (int idx = t; idx < PPB * 64; idx += TPB) {
      int pt_ = idx >> 6, k = idx & 63;
      float h = sf[pt_][0] * W0[k];
      #pragma unroll
      for (int i = 1; i < 10; ++i) h = fmaf(sf[pt_][i], W0[i * 64 + k], h);
      sfeat[pt_][k] = fmaxf(fmaf(h, sc0[k], sh0[k]), 0.f);
    }
    for (int idx = t; idx < PPB * 64; idx += TPB) {
      int pt_ = idx >> 6, k = idx & 63;
      sfeat[pt_][64 + k] = vmax[(size_t)svid[pt_] * 64 + k];
    }
    __syncthreads();

    float a0 = 0.f, a1 = 0.f, a2 = 0.f, a3 = 0.f;
    for (int k = 0; k < 128; ++k) {
      float pf = sfeat[pl][k];
      float4 w = *reinterpret_cast<const float4*>(W1 + (size_t)k * 128 + cb * 4);
      a0 = fmaf(pf, w.x, a0);
      a1 = fmaf(pf, w.y, a1);
      a2 = fmaf(pf, w.z, a2);
      a3 = fmaf(pf, w.w, a3);
    }
    int c = cb * 4;
    p1[pl][c + 0] = fmaxf(fmaf(a0, sc1[c + 0], sh1[c + 0]), 0.f);
    p1[pl][c + 1] = fmaxf(fmaf(a1, sc1[c + 1], sh1[c + 1]), 0.f);
    p1[pl][c + 2] = fmaxf(fmaf(a2, sc1[c + 2], sh1[c + 2]), 0.f);
    p1[pl][c + 3] = fmaxf(fmaf(a3, sc1[c + 3], sh1[c + 3]), 0.f);
    __syncthreads();

    if (t < 128) {
      for (int i = 0; i < PPB; ++i) {
        int v = svid[i];
        if (v != curv) {
          if (curv >= 0) {
            unsigned int vstart = voxloc[curv] + bexc[curv >> 8];
            unsigned int n = (unsigned int)vcnt[curv];
            bool interior = (vstart >= sbeg) && (vstart + n <= sbeg + STRETCH);
            if (interior)
              outp[(size_t)curv * 128 + t] = curm;
            else
              atomicMax((unsigned int*)&outp[(size_t)curv * 128 + t],
                        __float_as_uint(curm));
          }
          curv = v;
          curm = p1[i][t];
        } else {
          curm = fmaxf(curm, p1[i][t]);
        }
      }
    }
    __syncthreads();
  }
  if (t < 128 && curv >= 0) {
    unsigned int vstart = voxloc[curv] + bexc[curv >> 8];
    unsigned int n = (unsigned int)vcnt[curv];
    bool interior = (vstart >= sbeg) && (vstart + n <= sbeg + STRETCH);
    if (interior)
      outp[(size_t)curv * 128 + t] = curm;
    else
      atomicMax((unsigned int*)&outp[(size_t)curv * 128 + t],
                __float_as_uint(curm));
  }
}

extern "C" void kernel_launch(void* const* d_in, const int* in_sizes, int n_in,
                              void* d_out, int out_size, void* d_ws, size_t ws_size,
                              hipStream_t stream) {
  const float* pts = (const float*)d_in[0];
  const float* W0  = (const float*)d_in[1];
  const float* g0  = (const float*)d_in[2];
  const float* b0  = (const float*)d_in[3];
  const float* W1  = (const float*)d_in[4];
  const float* g1  = (const float*)d_in[5];
  const float* b1  = (const float*)d_in[6];

  char* base = (char*)d_ws;
  double* stats = (double*)base;
  float*  fold  = (float*)(base + 3072);
  float*  vcnt  = (float*)(base + 4608);
  float*  vsx   = vcnt + NVOX;
  float*  vsy   = vsx + NVOX;
  float*  vsz   = vsy + NVOX;
  float*  vmax  = vsz + NVOX;                          // NVOX*64 f32 (72MB)
  unsigned int* voxloc = (unsigned int*)(vmax + (size_t)NVOX * 64);
  unsigned int* cursor = voxloc + NVOX;
  unsigned int* plist  = cursor + NVOX;
  unsigned int* bsum   = plist + NPTS;
  unsigned int* bexc   = bsum + SCANB;

  double* s0 = stats,       *q0 = stats + 64;
  double* s1 = stats + 128, *q1 = stats + 256;
  float* sc0 = fold,       *sh0 = fold + 64;
  float* sc1 = fold + 128, *sh1 = fold + 256;

  hipMemsetAsync(stats, 0, 3072, stream);
  hipMemsetAsync(vcnt, 0, (size_t)4 * NVOX * sizeof(float), stream);
  hipMemsetAsync(vmax, 0, (size_t)NVOX * 64 * sizeof(float), stream);
  hipMemsetAsync(cursor, 0, (size_t)NVOX * sizeof(unsigned int), stream);
  hipMemsetAsync(d_out, 0, (size_t)out_size * sizeof(float), stream);

  voxsum<<<NBLK, TPB, 0, stream>>>(pts, vcnt, vsx, vsy, vsz);
  scan1<<<SCANB, 256, 0, stream>>>(vcnt, voxloc, bsum);
  scan2<<<1, 64, 0, stream>>>(bsum, bexc);
  scatter<<<NBLK, TPB, 0, stream>>>(pts, voxloc, bexc, cursor, plist);
  bn0stats<<<NBLK, TPB, 0, stream>>>(pts, vcnt, vsx, vsy, vsz, W0, s0, q0);
  bnfold<<<1, 64, 0, stream>>>(s0, q0, g0, b0, sc0, sh0, 64);
  vmax0_vox<<<NVOX, 64, 0, stream>>>(pts, vcnt, vsx, vsy, vsz, voxloc, bexc,
                                     plist, W0, sc0, sh0, vmax);
  gemm1s<<<SBLK, TPB, 0, stream>>>(pts, vcnt, vsx, vsy, vsz, W0, sc0, sh0,
                                   vmax, W1, s1, q1);
  bnfold<<<1, 128, 0, stream>>>(s1, q1, g1, b1, sc1, sh1, 128);
  final_sorted<<<FBLK, TPB, 0, stream>>>(pts, vcnt, vsx, vsy, vsz, voxloc, bexc,
                                         plist, W0, sc0, sh0, vmax, W1, sc1, sh1,
                                         (float*)d_out);
}

// Round 12
// 833.677 us; speedup vs baseline: 5.8328x; 2.2251x over previous
//
#include <hip/hip_runtime.h>
#include <stdint.h>

#define NPTS 400000
#define NVOX 281600
#define TPB  256
#define NBLK ((NPTS + TPB - 1) / TPB)
#define SCANB (NVOX / 256)       // 1100 exact
#define STRETCH 64
#define FBLK (NPTS / STRETCH)    // 6250 exact
#define SBLK2 1024               // stats grid (grid-stride over FBLK tiles)

// XLA-style binning: division folded to multiply-by-reciprocal in f32.
// DO NOT CHANGE: exactly matches the golden (round 6->7 proof).
__device__ __forceinline__ int bin3(const float* __restrict__ pt,
                                    int& bx, int& by, int& bz) {
  float x = pt[1], y = pt[2], z = pt[3];
  bx = (int)fminf(fmaxf(floorf(x * 5.0f), 0.f), 351.f);
  by = (int)fminf(fmaxf(floorf((y + 40.f) * 5.0f), 0.f), 399.f);
  bz = (int)fminf(fmaxf(floorf((z + 3.f) * 0.25f), 0.f), 0.f);
  return (((int)pt[0] + bz) * 400 + by) * 352 + bx;
}

__device__ __forceinline__ int mkfeat(const float* __restrict__ pt,
    const float* __restrict__ vcnt, const float* __restrict__ vsx,
    const float* __restrict__ vsy, const float* __restrict__ vsz,
    float* f) {
  int bx, by, bz;
  int v = bin3(pt, bx, by, bz);
  float x = pt[1], y = pt[2], z = pt[3];
  float n = fmaxf(vcnt[v], 1.f);
  f[0] = x;  f[1] = y;  f[2] = z;  f[3] = pt[4];
  f[4] = x - vsx[v] / n;
  f[5] = y - vsy[v] / n;
  f[6] = z - vsz[v] / n;
  f[7] = x - (0.2f * (float)bx + 0.1f);
  f[8] = y - (0.2f * (float)by - 39.9f);
  f[9] = z - (4.0f * (float)bz - 1.0f);
  return v;
}

// ---------------- prologue (verbatim, proven) ----------------
__global__ __launch_bounds__(256) void voxsum(const float* __restrict__ pts,
    float* __restrict__ vcnt, float* __restrict__ vsx,
    float* __restrict__ vsy, float* __restrict__ vsz) {
  int p = blockIdx.x * TPB + threadIdx.x;
  if (p >= NPTS) return;
  const float* pt = pts + (size_t)p * 5;
  int bx, by, bz;
  int v = bin3(pt, bx, by, bz);
  atomicAdd(&vcnt[v], 1.f);
  atomicAdd(&vsx[v], pt[1]);
  atomicAdd(&vsy[v], pt[2]);
  atomicAdd(&vsz[v], pt[3]);
}

__global__ __launch_bounds__(256) void bn0stats(const float* __restrict__ pts,
    const float* __restrict__ vcnt, const float* __restrict__ vsx,
    const float* __restrict__ vsy, const float* __restrict__ vsz,
    const float* __restrict__ W0,
    double* __restrict__ gs, double* __restrict__ gq) {
  __shared__ float bs[4][64], bq[4][64];
  int t = threadIdx.x, wv = t >> 6, ln = t & 63;
  int p = blockIdx.x * TPB + t;
  bool ok = p < NPTS;
  const float* pt = pts + (size_t)(ok ? p : 0) * 5;
  float f[10];
  mkfeat(pt, vcnt, vsx, vsy, vsz, f);
  for (int c = 0; c < 64; ++c) {
    float h = f[0] * W0[c];
    #pragma unroll
    for (int i = 1; i < 10; ++i) h = fmaf(f[i], W0[i * 64 + c], h);
    h = ok ? h : 0.f;
    float q = h * h;
    #pragma unroll
    for (int m = 1; m < 64; m <<= 1) {
      h += __shfl_xor(h, m, 64);
      q += __shfl_xor(q, m, 64);
    }
    if (ln == 0) { bs[wv][c] = h; bq[wv][c] = q; }
  }
  __syncthreads();
  if (t < 64) {
    atomicAdd(&gs[t], (double)bs[0][t] + bs[1][t] + bs[2][t] + bs[3][t]);
    atomicAdd(&gq[t], (double)bq[0][t] + bq[1][t] + bq[2][t] + bq[3][t]);
  }
}

__global__ void bnfold(const double* __restrict__ gs, const double* __restrict__ gq,
                       const float* __restrict__ gam, const float* __restrict__ bet,
                       float* __restrict__ sc, float* __restrict__ sh, int C) {
  int c = threadIdx.x;
  if (c >= C) return;
  double mu  = gs[c] / (double)NPTS;
  double var = gq[c] / (double)NPTS - mu * mu;
  double s = (double)gam[c] / sqrt(var + 1e-3);
  sc[c] = (float)s;
  sh[c] = (float)((double)bet[c] - mu * s);
}

// ---------------- counting sort ----------------
__global__ __launch_bounds__(256) void scan1(const float* __restrict__ vcnt,
    unsigned int* __restrict__ voxloc, unsigned int* __restrict__ bsum) {
  __shared__ unsigned int s[256];
  int t = threadIdx.x;
  int i = blockIdx.x * 256 + t;
  unsigned int val = (unsigned int)vcnt[i];
  s[t] = val;
  __syncthreads();
  for (int off = 1; off < 256; off <<= 1) {
    unsigned int add = (t >= off) ? s[t - off] : 0u;
    __syncthreads();
    s[t] += add;
    __syncthreads();
  }
  voxloc[i] = s[t] - val;
  if (t == 255) bsum[blockIdx.x] = s[t];
}

__global__ void scan2(const unsigned int* __restrict__ bsum,
                      unsigned int* __restrict__ bexc) {
  if (threadIdx.x != 0) return;
  unsigned int run = 0;
  for (int b = 0; b < SCANB; ++b) { bexc[b] = run; run += bsum[b]; }
}

__global__ __launch_bounds__(256) void scatter(const float* __restrict__ pts,
    const unsigned int* __restrict__ voxloc, const unsigned int* __restrict__ bexc,
    unsigned int* __restrict__ cursor, unsigned int* __restrict__ plist) {
  int p = blockIdx.x * TPB + threadIdx.x;
  if (p >= NPTS) return;
  int bx, by, bz;
  int v = bin3(pts + (size_t)p * 5, bx, by, bz);
  unsigned int pos = voxloc[v] + bexc[v >> 8] + atomicAdd(&cursor[v], 1u);
  plist[pos] = (unsigned int)p;
}

// ---------------- vmax0 over sorted stretches ----------------
__global__ __launch_bounds__(256) void vmax0_stretch(const float* __restrict__ pts,
    const float* __restrict__ vcnt, const float* __restrict__ vsx,
    const float* __restrict__ vsy, const float* __restrict__ vsz,
    const unsigned int* __restrict__ voxloc, const unsigned int* __restrict__ bexc,
    const unsigned int* __restrict__ plist,
    const float* __restrict__ W0, const float* __restrict__ sc0,
    const float* __restrict__ sh0, float* __restrict__ vmax) {
  __shared__ float sf[STRETCH][12];
  __shared__ int   svid[STRETCH];
  __shared__ float pf[STRETCH][64];
  int t = threadIdx.x;
  unsigned int sbeg = blockIdx.x * STRETCH;

  if (t < STRETCH) {
    unsigned int pidx = plist[sbeg + t];
    svid[t] = mkfeat(pts + (size_t)pidx * 5, vcnt, vsx, vsy, vsz, &sf[t][0]);
  }
  __syncthreads();
  for (int idx = t; idx < STRETCH * 64; idx += TPB) {
    int pt_ = idx >> 6, k = idx & 63;
    float h = sf[pt_][0] * W0[k];
    #pragma unroll
    for (int i = 1; i < 10; ++i) h = fmaf(sf[pt_][i], W0[i * 64 + k], h);
    pf[pt_][k] = fmaxf(fmaf(h, sc0[k], sh0[k]), 0.f);
  }
  __syncthreads();

  if (t < 64) {
    int curv = -1; float curm = 0.f;
    for (int i = 0; i < STRETCH; ++i) {
      int v = svid[i];
      if (v != curv) {
        if (curv >= 0) {
          unsigned int vstart = voxloc[curv] + bexc[curv >> 8];
          unsigned int n = (unsigned int)vcnt[curv];
          if (vstart >= sbeg && vstart + n <= sbeg + STRETCH)
            vmax[(size_t)curv * 64 + t] = curm;
          else
            atomicMax((unsigned int*)&vmax[(size_t)curv * 64 + t],
                      __float_as_uint(curm));
        }
        curv = v;
        curm = pf[i][t];
      } else {
        curm = fmaxf(curm, pf[i][t]);
      }
    }
    if (curv >= 0) {
      unsigned int vstart = voxloc[curv] + bexc[curv >> 8];
      unsigned int n = (unsigned int)vcnt[curv];
      if (vstart >= sbeg && vstart + n <= sbeg + STRETCH)
        vmax[(size_t)curv * 64 + t] = curm;
      else
        atomicMax((unsigned int*)&vmax[(size_t)curv * 64 + t],
                  __float_as_uint(curm));
    }
  }
}

// ---- shared tile staging + GEMM body (64 pts, 8 pts x 4 ch per thread) ----
// A0..A7: named float4 accumulators (register-resident by construction).
#define TILE_STAGE(sbeg_)                                                    \
  if (t < STRETCH) {                                                         \
    unsigned int pidx = plist[(sbeg_) + t];                                  \
    svid[t] = mkfeat(pts + (size_t)pidx * 5, vcnt, vsx, vsy, vsz, &sf[t][0]);\
  }                                                                          \
  __syncthreads();                                                           \
  for (int idx = t; idx < STRETCH * 64; idx += TPB) {                        \
    int pt_ = idx >> 6, k = idx & 63;                                        \
    float h = sf[pt_][0] * W0[k];                                            \
    _Pragma("unroll")                                                        \
    for (int i = 1; i < 10; ++i) h = fmaf(sf[pt_][i], W0[i * 64 + k], h);    \
    sfeat[pt_][k] = fmaxf(fmaf(h, sc0[k], sh0[k]), 0.f);                     \
  }                                                                          \
  for (int idx = t; idx < STRETCH * 64; idx += TPB) {                        \
    int pt_ = idx >> 6, k = idx & 63;                                        \
    sfeat[pt_][64 + k] = vmax[(size_t)svid[pt_] * 64 + k];                   \
  }                                                                          \
  __syncthreads();

#define TILE_GEMM()                                                          \
  const float* r0 = sfeat[pg * 8 + 0];                                       \
  const float* r1 = sfeat[pg * 8 + 1];                                       \
  const float* r2 = sfeat[pg * 8 + 2];                                       \
  const float* r3 = sfeat[pg * 8 + 3];                                       \
  const float* r4 = sfeat[pg * 8 + 4];                                       \
  const float* r5 = sfeat[pg * 8 + 5];                                       \
  const float* r6 = sfeat[pg * 8 + 6];                                       \
  const float* r7 = sfeat[pg * 8 + 7];                                       \
  float4 A0 = {0,0,0,0}, A1 = {0,0,0,0}, A2 = {0,0,0,0}, A3 = {0,0,0,0};     \
  float4 A4 = {0,0,0,0}, A5 = {0,0,0,0}, A6 = {0,0,0,0}, A7 = {0,0,0,0};     \
  _Pragma("unroll 8")                                                        \
  for (int k = 0; k < 128; ++k) {                                            \
    float4 w = *reinterpret_cast<const float4*>(W1 + (size_t)k * 128 + cb*4);\
    float p0 = r0[k], p1_ = r1[k], p2 = r2[k], p3 = r3[k];                   \
    float p4 = r4[k], p5 = r5[k], p6 = r6[k], p7 = r7[k];                    \
    A0.x = fmaf(p0, w.x, A0.x); A0.y = fmaf(p0, w.y, A0.y);                  \
    A0.z = fmaf(p0, w.z, A0.z); A0.w = fmaf(p0, w.w, A0.w);                  \
    A1.x = fmaf(p1_, w.x, A1.x); A1.y = fmaf(p1_, w.y, A1.y);                \
    A1.z = fmaf(p1_, w.z, A1.z); A1.w = fmaf(p1_, w.w, A1.w);                \
    A2.x = fmaf(p2, w.x, A2.x); A2.y = fmaf(p2, w.y, A2.y);                  \
    A2.z = fmaf(p2, w.z, A2.z); A2.w = fmaf(p2, w.w, A2.w);                  \
    A3.x = fmaf(p3, w.x, A3.x); A3.y = fmaf(p3, w.y, A3.y);                  \
    A3.z = fmaf(p3, w.z, A3.z); A3.w = fmaf(p3, w.w, A3.w);                  \
    A4.x = fmaf(p4, w.x, A4.x); A4.y = fmaf(p4, w.y, A4.y);                  \
    A4.z = fmaf(p4, w.z, A4.z); A4.w = fmaf(p4, w.w, A4.w);                  \
    A5.x = fmaf(p5, w.x, A5.x); A5.y = fmaf(p5, w.y, A5.y);                  \
    A5.z = fmaf(p5, w.z, A5.z); A5.w = fmaf(p5, w.w, A5.w);                  \
    A6.x = fmaf(p6, w.x, A6.x); A6.y = fmaf(p6, w.y, A6.y);                  \
    A6.z = fmaf(p6, w.z, A6.z); A6.w = fmaf(p6, w.w, A6.w);                  \
    A7.x = fmaf(p7, w.x, A7.x); A7.y = fmaf(p7, w.y, A7.y);                  \
    A7.z = fmaf(p7, w.z, A7.z); A7.w = fmaf(p7, w.w, A7.w);                  \
  }

// ---------------- BN1 stats over tiles (grid-stride) ----------------
__global__ __launch_bounds__(256) void gemm1s(const float* __restrict__ pts,
    const float* __restrict__ vcnt, const float* __restrict__ vsx,
    const float* __restrict__ vsy, const float* __restrict__ vsz,
    const unsigned int* __restrict__ plist,
    const float* __restrict__ W0, const float* __restrict__ sc0,
    const float* __restrict__ sh0, const float* __restrict__ vmax,
    const float* __restrict__ W1,
    double* __restrict__ gs, double* __restrict__ gq) {
  __shared__ float sf[STRETCH][12];
  __shared__ int   svid[STRETCH];
  __shared__ float sfeat[STRETCH][128];
  __shared__ double lsum[8 * 128];
  __shared__ double lsq [8 * 128];

  int t = threadIdx.x;
  int pg = t >> 5, cb = t & 31;
  double sd0 = 0, sd1 = 0, sd2 = 0, sd3 = 0;
  double qd0 = 0, qd1 = 0, qd2 = 0, qd3 = 0;

  for (int tile = blockIdx.x; tile < FBLK; tile += gridDim.x) {
    unsigned int sbeg = tile * STRETCH;
    TILE_STAGE(sbeg)
    TILE_GEMM()
    sd0 += (double)A0.x + (double)A1.x + (double)A2.x + (double)A3.x
         + (double)A4.x + (double)A5.x + (double)A6.x + (double)A7.x;
    sd1 += (double)A0.y + (double)A1.y + (double)A2.y + (double)A3.y
         + (double)A4.y + (double)A5.y + (double)A6.y + (double)A7.y;
    sd2 += (double)A0.z + (double)A1.z + (double)A2.z + (double)A3.z
         + (double)A4.z + (double)A5.z + (double)A6.z + (double)A7.z;
    sd3 += (double)A0.w + (double)A1.w + (double)A2.w + (double)A3.w
         + (double)A4.w + (double)A5.w + (double)A6.w + (double)A7.w;
    qd0 += (double)A0.x*A0.x + (double)A1.x*A1.x + (double)A2.x*A2.x + (double)A3.x*A3.x
         + (double)A4.x*A4.x + (double)A5.x*A5.x + (double)A6.x*A6.x + (double)A7.x*A7.x;
    qd1 += (double)A0.y*A0.y + (double)A1.y*A1.y + (double)A2.y*A2.y + (double)A3.y*A3.y
         + (double)A4.y*A4.y + (double)A5.y*A5.y + (double)A6.y*A6.y + (double)A7.y*A7.y;
    qd2 += (double)A0.z*A0.z + (double)A1.z*A1.z + (double)A2.z*A2.z + (double)A3.z*A3.z
         + (double)A4.z*A4.z + (double)A5.z*A5.z + (double)A6.z*A6.z + (double)A7.z*A7.z;
    qd3 += (double)A0.w*A0.w + (double)A1.w*A1.w + (double)A2.w*A2.w + (double)A3.w*A3.w
         + (double)A4.w*A4.w + (double)A5.w*A5.w + (double)A6.w*A6.w + (double)A7.w*A7.w;
    __syncthreads();
  }

  int c = cb * 4;
  lsum[pg * 128 + c + 0] = sd0;  lsq[pg * 128 + c + 0] = qd0;
  lsum[pg * 128 + c + 1] = sd1;  lsq[pg * 128 + c + 1] = qd1;
  lsum[pg * 128 + c + 2] = sd2;  lsq[pg * 128 + c + 2] = qd2;
  lsum[pg * 128 + c + 3] = sd3;  lsq[pg * 128 + c + 3] = qd3;
  __syncthreads();
  if (t < 128) {
    double S = 0, Q = 0;
    #pragma unroll
    for (int j = 0; j < 8; ++j) { S += lsum[j * 128 + t]; Q += lsq[j * 128 + t]; }
    atomicAdd(&gs[t], S);
    atomicAdd(&gq[t], Q);
  }
}

// ---------------- final pass: tile GEMM + segmented max ----------------
__global__ __launch_bounds__(256) void final2(const float* __restrict__ pts,
    const float* __restrict__ vcnt, const float* __restrict__ vsx,
    const float* __restrict__ vsy, const float* __restrict__ vsz,
    const unsigned int* __restrict__ voxloc, const unsigned int* __restrict__ bexc,
    const unsigned int* __restrict__ plist,
    const float* __restrict__ W0, const float* __restrict__ sc0,
    const float* __restrict__ sh0, const float* __restrict__ vmax,
    const float* __restrict__ W1, const float* __restrict__ sc1,
    const float* __restrict__ sh1, float* __restrict__ outp) {
  __shared__ float sf[STRETCH][12];
  __shared__ int   svid[STRETCH];
  __shared__ float sfeat[STRETCH][128];   // reused as p1 after the GEMM

  int t = threadIdx.x;
  int pg = t >> 5, cb = t & 31;
  unsigned int sbeg = blockIdx.x * STRETCH;

  TILE_STAGE(sbeg)
  TILE_GEMM()
  __syncthreads();   // all sfeat reads done; safe to overwrite with p1

  int c = cb * 4;
  float4 s1v = *reinterpret_cast<const float4*>(sc1 + c);
  float4 h1v = *reinterpret_cast<const float4*>(sh1 + c);
  float4 P;
  P.x = fmaxf(fmaf(A0.x, s1v.x, h1v.x), 0.f);
  P.y = fmaxf(fmaf(A0.y, s1v.y, h1v.y), 0.f);
  P.z = fmaxf(fmaf(A0.z, s1v.z, h1v.z), 0.f);
  P.w = fmaxf(fmaf(A0.w, s1v.w, h1v.w), 0.f);
  *reinterpret_cast<float4*>(&sfeat[pg * 8 + 0][c]) = P;
  P.x = fmaxf(fmaf(A1.x, s1v.x, h1v.x), 0.f);
  P.y = fmaxf(fmaf(A1.y, s1v.y, h1v.y), 0.f);
  P.z = fmaxf(fmaf(A1.z, s1v.z, h1v.z), 0.f);
  P.w = fmaxf(fmaf(A1.w, s1v.w, h1v.w), 0.f);
  *reinterpret_cast<float4*>(&sfeat[pg * 8 + 1][c]) = P;
  P.x = fmaxf(fmaf(A2.x, s1v.x, h1v.x), 0.f);
  P.y = fmaxf(fmaf(A2.y, s1v.y, h1v.y), 0.f);
  P.z = fmaxf(fmaf(A2.z, s1v.z, h1v.z), 0.f);
  P.w = fmaxf(fmaf(A2.w, s1v.w, h1v.w), 0.f);
  *reinterpret_cast<float4*>(&sfeat[pg * 8 + 2][c]) = P;
  P.x = fmaxf(fmaf(A3.x, s1v.x, h1v.x), 0.f);
  P.y = fmaxf(fmaf(A3.y, s1v.y, h1v.y), 0.f);
  P.z = fmaxf(fmaf(A3.z, s1v.z, h1v.z), 0.f);
  P.w = fmaxf(fmaf(A3.w, s1v.w, h1v.w), 0.f);
  *reinterpret_cast<float4*>(&sfeat[pg * 8 + 3][c]) = P;
  P.x = fmaxf(fmaf(A4.x, s1v.x, h1v.x), 0.f);
  P.y = fmaxf(fmaf(A4.y, s1v.y, h1v.y), 0.f);
  P.z = fmaxf(fmaf(A4.z, s1v.z, h1v.z), 0.f);
  P.w = fmaxf(fmaf(A4.w, s1v.w, h1v.w), 0.f);
  *reinterpret_cast<float4*>(&sfeat[pg * 8 + 4][c]) = P;
  P.x = fmaxf(fmaf(A5.x, s1v.x, h1v.x), 0.f);
  P.y = fmaxf(fmaf(A5.y, s1v.y, h1v.y), 0.f);
  P.z = fmaxf(fmaf(A5.z, s1v.z, h1v.z), 0.f);
  P.w = fmaxf(fmaf(A5.w, s1v.w, h1v.w), 0.f);
  *reinterpret_cast<float4*>(&sfeat[pg * 8 + 5][c]) = P;
  P.x = fmaxf(fmaf(A6.x, s1v.x, h1v.x), 0.f);
  P.y = fmaxf(fmaf(A6.y, s1v.y, h1v.y), 0.f);
  P.z = fmaxf(fmaf(A6.z, s1v.z, h1v.z), 0.f);
  P.w = fmaxf(fmaf(A6.w, s1v.w, h1v.w), 0.f);
  *reinterpret_cast<float4*>(&sfeat[pg * 8 + 6][c]) = P;
  P.x = fmaxf(fmaf(A7.x, s1v.x, h1v.x), 0.f);
  P.y = fmaxf(fmaf(A7.y, s1v.y, h1v.y), 0.f);
  P.z = fmaxf(fmaf(A7.z, s1v.z, h1v.z), 0.f);
  P.w = fmaxf(fmaf(A7.w, s1v.w, h1v.w), 0.f);
  *reinterpret_cast<float4*>(&sfeat[pg * 8 + 7][c]) = P;
  __syncthreads();

  if (t < 128) {
    int curv = -1; float curm = 0.f;
    for (int i = 0; i < STRETCH; ++i) {
      int v = svid[i];
      if (v != curv) {
        if (curv >= 0) {
          unsigned int vstart = voxloc[curv] + bexc[curv >> 8];
          unsigned int n = (unsigned int)vcnt[curv];
          if (vstart >= sbeg && vstart + n <= sbeg + STRETCH)
            outp[(size_t)curv * 128 + t] = curm;
          else
            atomicMax((unsigned int*)&outp[(size_t)curv * 128 + t],
                      __float_as_uint(curm));
        }
        curv = v;
        curm = sfeat[i][t];
      } else {
        curm = fmaxf(curm, sfeat[i][t]);
      }
    }
    if (curv >= 0) {
      unsigned int vstart = voxloc[curv] + bexc[curv >> 8];
      unsigned int n = (unsigned int)vcnt[curv];
      if (vstart >= sbeg && vstart + n <= sbeg + STRETCH)
        outp[(size_t)curv * 128 + t] = curm;
      else
        atomicMax((unsigned int*)&outp[(size_t)curv * 128 + t],
                  __float_as_uint(curm));
    }
  }
}

extern "C" void kernel_launch(void* const* d_in, const int* in_sizes, int n_in,
                              void* d_out, int out_size, void* d_ws, size_t ws_size,
                              hipStream_t stream) {
  const float* pts = (const float*)d_in[0];
  const float* W0  = (const float*)d_in[1];
  const float* g0  = (const float*)d_in[2];
  const float* b0  = (const float*)d_in[3];
  const float* W1  = (const float*)d_in[4];
  const float* g1  = (const float*)d_in[5];
  const float* b1  = (const float*)d_in[6];

  char* base = (char*)d_ws;
  double* stats = (double*)base;
  float*  fold  = (float*)(base + 3072);
  float*  vcnt  = (float*)(base + 4608);
  float*  vsx   = vcnt + NVOX;
  float*  vsy   = vsx + NVOX;
  float*  vsz   = vsy + NVOX;
  float*  vmax  = vsz + NVOX;                          // NVOX*64 f32 (72MB)
  unsigned int* voxloc = (unsigned int*)(vmax + (size_t)NVOX * 64);
  unsigned int* cursor = voxloc + NVOX;
  unsigned int* plist  = cursor + NVOX;
  unsigned int* bsum   = plist + NPTS;
  unsigned int* bexc   = bsum + SCANB;

  double* s0 = stats,       *q0 = stats + 64;
  double* s1 = stats + 128, *q1 = stats + 256;
  float* sc0 = fold,       *sh0 = fold + 64;
  float* sc1 = fold + 128, *sh1 = fold + 256;

  hipMemsetAsync(stats, 0, 3072, stream);
  hipMemsetAsync(vcnt, 0, (size_t)4 * NVOX * sizeof(float), stream);
  hipMemsetAsync(vmax, 0, (size_t)NVOX * 64 * sizeof(float), stream);
  hipMemsetAsync(cursor, 0, (size_t)NVOX * sizeof(unsigned int), stream);
  hipMemsetAsync(d_out, 0, (size_t)out_size * sizeof(float), stream);

  voxsum<<<NBLK, TPB, 0, stream>>>(pts, vcnt, vsx, vsy, vsz);
  scan1<<<SCANB, 256, 0, stream>>>(vcnt, voxloc, bsum);
  scan2<<<1, 64, 0, stream>>>(bsum, bexc);
  scatter<<<NBLK, TPB, 0, stream>>>(pts, voxloc, bexc, cursor, plist);
  bn0stats<<<NBLK, TPB, 0, stream>>>(pts, vcnt, vsx, vsy, vsz, W0, s0, q0);
  bnfold<<<1, 64, 0, stream>>>(s0, q0, g0, b0, sc0, sh0, 64);
  vmax0_stretch<<<FBLK, TPB, 0, stream>>>(pts, vcnt, vsx, vsy, vsz, voxloc, bexc,
                                          plist, W0, sc0, sh0, vmax);
  gemm1s<<<SBLK2, TPB, 0, stream>>>(pts, vcnt, vsx, vsy, vsz, plist,
                                    W0, sc0, sh0, vmax, W1, s1, q1);
  bnfold<<<1, 128, 0, stream>>>(s1, q1, g1, b1, sc1, sh1, 128);
  final2<<<FBLK, TPB, 0, stream>>>(pts, vcnt, vsx, vsy, vsz, voxloc, bexc,
                                   plist, W0, sc0, sh0, vmax, W1, sc1, sh1,
                                   (float*)d_out);
}

// Round 13
// 617.839 us; speedup vs baseline: 7.8705x; 1.3493x over previous
//
#include <hip/hip_runtime.h>
#include <hip/hip_fp16.h>
#include <stdint.h>

#define NPTS 400000
#define NVOX 281600
#define TPB  256
#define NBLK ((NPTS + TPB - 1) / TPB)
#define SCANB (NVOX / 256)       // 1100 exact
#define STRETCH 64
#define FBLK (NPTS / STRETCH)    // 6250 exact
#define SBLK2 1024

// XLA-style binning: division folded to multiply-by-reciprocal in f32.
// DO NOT CHANGE: exactly matches the golden (round 6->7 proof).
__device__ __forceinline__ int bin3(const float* __restrict__ pt,
                                    int& bx, int& by, int& bz) {
  float x = pt[1], y = pt[2], z = pt[3];
  bx = (int)fminf(fmaxf(floorf(x * 5.0f), 0.f), 351.f);
  by = (int)fminf(fmaxf(floorf((y + 40.f) * 5.0f), 0.f), 399.f);
  bz = (int)fminf(fmaxf(floorf((z + 3.f) * 0.25f), 0.f), 0.f);
  return (((int)pt[0] + bz) * 400 + by) * 352 + bx;
}

__device__ __forceinline__ int mkfeat(const float* __restrict__ pt,
    const float* __restrict__ vcnt, const float* __restrict__ vsx,
    const float* __restrict__ vsy, const float* __restrict__ vsz,
    float* f) {
  int bx, by, bz;
  int v = bin3(pt, bx, by, bz);
  float x = pt[1], y = pt[2], z = pt[3];
  float n = fmaxf(vcnt[v], 1.f);
  f[0] = x;  f[1] = y;  f[2] = z;  f[3] = pt[4];
  f[4] = x - vsx[v] / n;
  f[5] = y - vsy[v] / n;
  f[6] = z - vsz[v] / n;
  f[7] = x - (0.2f * (float)bx + 0.1f);
  f[8] = y - (0.2f * (float)by - 39.9f);
  f[9] = z - (4.0f * (float)bz - 1.0f);
  return v;
}

// ---------------- prologue ----------------
__global__ __launch_bounds__(256) void voxsum(const float* __restrict__ pts,
    float* __restrict__ vcnt, float* __restrict__ vsx,
    float* __restrict__ vsy, float* __restrict__ vsz) {
  int p = blockIdx.x * TPB + threadIdx.x;
  if (p >= NPTS) return;
  const float* pt = pts + (size_t)p * 5;
  int bx, by, bz;
  int v = bin3(pt, bx, by, bz);
  atomicAdd(&vcnt[v], 1.f);
  atomicAdd(&vsx[v], pt[1]);
  atomicAdd(&vsy[v], pt[2]);
  atomicAdd(&vsz[v], pt[3]);
}

__global__ __launch_bounds__(256) void bn0stats(const float* __restrict__ pts,
    const float* __restrict__ vcnt, const float* __restrict__ vsx,
    const float* __restrict__ vsy, const float* __restrict__ vsz,
    const float* __restrict__ W0,
    double* __restrict__ gs, double* __restrict__ gq) {
  __shared__ float bs[4][64], bq[4][64];
  int t = threadIdx.x, wv = t >> 6, ln = t & 63;
  int p = blockIdx.x * TPB + t;
  bool ok = p < NPTS;
  const float* pt = pts + (size_t)(ok ? p : 0) * 5;
  float f[10];
  mkfeat(pt, vcnt, vsx, vsy, vsz, f);
  for (int c = 0; c < 64; ++c) {
    float h = f[0] * W0[c];
    #pragma unroll
    for (int i = 1; i < 10; ++i) h = fmaf(f[i], W0[i * 64 + c], h);
    h = ok ? h : 0.f;
    float q = h * h;
    #pragma unroll
    for (int m = 1; m < 64; m <<= 1) {
      h += __shfl_xor(h, m, 64);
      q += __shfl_xor(q, m, 64);
    }
    if (ln == 0) { bs[wv][c] = h; bq[wv][c] = q; }
  }
  __syncthreads();
  if (t < 64) {
    atomicAdd(&gs[t], (double)bs[0][t] + bs[1][t] + bs[2][t] + bs[3][t]);
    atomicAdd(&gq[t], (double)bq[0][t] + bq[1][t] + bq[2][t] + bq[3][t]);
  }
}

__global__ void bnfold(const double* __restrict__ gs, const double* __restrict__ gq,
                       const float* __restrict__ gam, const float* __restrict__ bet,
                       float* __restrict__ sc, float* __restrict__ sh, int C) {
  int c = threadIdx.x;
  if (c >= C) return;
  double mu  = gs[c] / (double)NPTS;
  double var = gq[c] / (double)NPTS - mu * mu;
  double s = (double)gam[c] / sqrt(var + 1e-3);
  sc[c] = (float)s;
  sh[c] = (float)((double)bet[c] - mu * s);
}

// ---------------- counting sort ----------------
__global__ __launch_bounds__(256) void scan1(const float* __restrict__ vcnt,
    unsigned int* __restrict__ voxloc, unsigned int* __restrict__ bsum) {
  __shared__ unsigned int s[256];
  int t = threadIdx.x;
  int i = blockIdx.x * 256 + t;
  unsigned int val = (unsigned int)vcnt[i];
  s[t] = val;
  __syncthreads();
  for (int off = 1; off < 256; off <<= 1) {
    unsigned int add = (t >= off) ? s[t - off] : 0u;
    __syncthreads();
    s[t] += add;
    __syncthreads();
  }
  voxloc[i] = s[t] - val;
  if (t == 255) bsum[blockIdx.x] = s[t];
}

__global__ void scan2(const unsigned int* __restrict__ bsum,
                      unsigned int* __restrict__ bexc) {
  if (threadIdx.x != 0) return;
  unsigned int run = 0;
  for (int b = 0; b < SCANB; ++b) { bexc[b] = run; run += bsum[b]; }
}

__global__ __launch_bounds__(256) void scatter(const float* __restrict__ pts,
    const unsigned int* __restrict__ voxloc, const unsigned int* __restrict__ bexc,
    unsigned int* __restrict__ cursor, unsigned int* __restrict__ plist,
    unsigned int* __restrict__ vsort) {
  int p = blockIdx.x * TPB + threadIdx.x;
  if (p >= NPTS) return;
  int bx, by, bz;
  int v = bin3(pts + (size_t)p * 5, bx, by, bz);
  unsigned int pos = voxloc[v] + bexc[v >> 8] + atomicAdd(&cursor[v], 1u);
  plist[pos] = (unsigned int)p;
  vsort[pos] = (unsigned int)v;
}

// ---------------- vmax0 over sorted stretches ----------------
__global__ __launch_bounds__(256) void vmax0_stretch(const float* __restrict__ pts,
    const float* __restrict__ vcnt, const float* __restrict__ vsx,
    const float* __restrict__ vsy, const float* __restrict__ vsz,
    const unsigned int* __restrict__ voxloc, const unsigned int* __restrict__ bexc,
    const unsigned int* __restrict__ plist,
    const float* __restrict__ W0, const float* __restrict__ sc0,
    const float* __restrict__ sh0, float* __restrict__ vmax) {
  __shared__ float sf[STRETCH][12];
  __shared__ int   svid[STRETCH];
  __shared__ float pf[STRETCH][64];
  int t = threadIdx.x;
  unsigned int sbeg = blockIdx.x * STRETCH;

  if (t < STRETCH) {
    unsigned int pidx = plist[sbeg + t];
    svid[t] = mkfeat(pts + (size_t)pidx * 5, vcnt, vsx, vsy, vsz, &sf[t][0]);
  }
  __syncthreads();
  for (int idx = t; idx < STRETCH * 64; idx += TPB) {
    int pt_ = idx >> 6, k = idx & 63;
    float h = sf[pt_][0] * W0[k];
    #pragma unroll
    for (int i = 1; i < 10; ++i) h = fmaf(sf[pt_][i], W0[i * 64 + k], h);
    pf[pt_][k] = fmaxf(fmaf(h, sc0[k], sh0[k]), 0.f);
  }
  __syncthreads();

  if (t < 64) {
    int curv = -1; float curm = 0.f;
    for (int i = 0; i < STRETCH; ++i) {
      int v = svid[i];
      if (v != curv) {
        if (curv >= 0) {
          unsigned int vstart = voxloc[curv] + bexc[curv >> 8];
          unsigned int n = (unsigned int)vcnt[curv];
          if (vstart >= sbeg && vstart + n <= sbeg + STRETCH)
            vmax[(size_t)curv * 64 + t] = curm;
          else
            atomicMax((unsigned int*)&vmax[(size_t)curv * 64 + t],
                      __float_as_uint(curm));
        }
        curv = v;
        curm = pf[i][t];
      } else {
        curm = fmaxf(curm, pf[i][t]);
      }
    }
    if (curv >= 0) {
      unsigned int vstart = voxloc[curv] + bexc[curv >> 8];
      unsigned int n = (unsigned int)vcnt[curv];
      if (vstart >= sbeg && vstart + n <= sbeg + STRETCH)
        vmax[(size_t)curv * 64 + t] = curm;
      else
        atomicMax((unsigned int*)&vmax[(size_t)curv * 64 + t],
                  __float_as_uint(curm));
    }
  }
}

// ---- shared tile staging + GEMM body (64 pts, 8 pts x 4 ch per thread) ----
#define TILE_STAGE(sbeg_)                                                    \
  if (t < STRETCH) {                                                         \
    unsigned int pidx = plist[(sbeg_) + t];                                  \
    svid[t] = mkfeat(pts + (size_t)pidx * 5, vcnt, vsx, vsy, vsz, &sf[t][0]);\
  }                                                                          \
  __syncthreads();                                                           \
  for (int idx = t; idx < STRETCH * 64; idx += TPB) {                        \
    int pt_ = idx >> 6, k = idx & 63;                                        \
    float h = sf[pt_][0] * W0[k];                                            \
    _Pragma("unroll")                                                        \
    for (int i = 1; i < 10; ++i) h = fmaf(sf[pt_][i], W0[i * 64 + k], h);    \
    sfeat[pt_][k] = fmaxf(fmaf(h, sc0[k], sh0[k]), 0.f);                     \
  }                                                                          \
  for (int idx = t; idx < STRETCH * 64; idx += TPB) {                        \
    int pt_ = idx >> 6, k = idx & 63;                                        \
    sfeat[pt_][64 + k] = vmax[(size_t)svid[pt_] * 64 + k];                   \
  }                                                                          \
  __syncthreads();

#define TILE_GEMM()                                                          \
  const float* r0 = sfeat[pg * 8 + 0];                                       \
  const float* r1 = sfeat[pg * 8 + 1];                                       \
  const float* r2 = sfeat[pg * 8 + 2];                                       \
  const float* r3 = sfeat[pg * 8 + 3];                                       \
  const float* r4 = sfeat[pg * 8 + 4];                                       \
  const float* r5 = sfeat[pg * 8 + 5];                                       \
  const float* r6 = sfeat[pg * 8 + 6];                                       \
  const float* r7 = sfeat[pg * 8 + 7];                                       \
  float4 A0 = {0,0,0,0}, A1 = {0,0,0,0}, A2 = {0,0,0,0}, A3 = {0,0,0,0};     \
  float4 A4 = {0,0,0,0}, A5 = {0,0,0,0}, A6 = {0,0,0,0}, A7 = {0,0,0,0};     \
  _Pragma("unroll 8")                                                        \
  for (int k = 0; k < 128; ++k) {                                            \
    float4 w = *reinterpret_cast<const float4*>(W1 + (size_t)k * 128 + cb*4);\
    float p0 = r0[k], p1_ = r1[k], p2 = r2[k], p3 = r3[k];                   \
    float p4 = r4[k], p5 = r5[k], p6 = r6[k], p7 = r7[k];                    \
    A0.x = fmaf(p0, w.x, A0.x); A0.y = fmaf(p0, w.y, A0.y);                  \
    A0.z = fmaf(p0, w.z, A0.z); A0.w = fmaf(p0, w.w, A0.w);                  \
    A1.x = fmaf(p1_, w.x, A1.x); A1.y = fmaf(p1_, w.y, A1.y);                \
    A1.z = fmaf(p1_, w.z, A1.z); A1.w = fmaf(p1_, w.w, A1.w);                \
    A2.x = fmaf(p2, w.x, A2.x); A2.y = fmaf(p2, w.y, A2.y);                  \
    A2.z = fmaf(p2, w.z, A2.z); A2.w = fmaf(p2, w.w, A2.w);                  \
    A3.x = fmaf(p3, w.x, A3.x); A3.y = fmaf(p3, w.y, A3.y);                  \
    A3.z = fmaf(p3, w.z, A3.z); A3.w = fmaf(p3, w.w, A3.w);                  \
    A4.x = fmaf(p4, w.x, A4.x); A4.y = fmaf(p4, w.y, A4.y);                  \
    A4.z = fmaf(p4, w.z, A4.z); A4.w = fmaf(p4, w.w, A4.w);                  \
    A5.x = fmaf(p5, w.x, A5.x); A5.y = fmaf(p5, w.y, A5.y);                  \
    A5.z = fmaf(p5, w.z, A5.z); A5.w = fmaf(p5, w.w, A5.w);                  \
    A6.x = fmaf(p6, w.x, A6.x); A6.y = fmaf(p6, w.y, A6.y);                  \
    A6.z = fmaf(p6, w.z, A6.z); A6.w = fmaf(p6, w.w, A6.w);                  \
    A7.x = fmaf(p7, w.x, A7.x); A7.y = fmaf(p7, w.y, A7.y);                  \
    A7.z = fmaf(p7, w.z, A7.z); A7.w = fmaf(p7, w.w, A7.w);                  \
  }

// ---------------- BN1 stats (+ optional h1 materialization) ----------------
template <int WRITE_H1>
__global__ __launch_bounds__(256) void gemm1s(const float* __restrict__ pts,
    const float* __restrict__ vcnt, const float* __restrict__ vsx,
    const float* __restrict__ vsy, const float* __restrict__ vsz,
    const unsigned int* __restrict__ plist,
    const float* __restrict__ W0, const float* __restrict__ sc0,
    const float* __restrict__ sh0, const float* __restrict__ vmax,
    const float* __restrict__ W1,
    double* __restrict__ gs, double* __restrict__ gq,
    __half* __restrict__ h1out) {
  union SM {
    struct { float sf[STRETCH][12]; int svid[STRETCH]; float sfeat[STRETCH][128]; } a;
    struct { double lsum[8 * 128]; double lsq[8 * 128]; } b;
  };
  __shared__ SM sm;
  auto& sf = sm.a.sf;
  auto& svid = sm.a.svid;
  auto& sfeat = sm.a.sfeat;

  int t = threadIdx.x;
  int pg = t >> 5, cb = t & 31;
  double sd0 = 0, sd1 = 0, sd2 = 0, sd3 = 0;
  double qd0 = 0, qd1 = 0, qd2 = 0, qd3 = 0;

  for (int tile = blockIdx.x; tile < FBLK; tile += gridDim.x) {
    unsigned int sbeg = tile * STRETCH;
    TILE_STAGE(sbeg)
    TILE_GEMM()
    if (WRITE_H1) {
      int c = cb * 4;
      #define H1ST(Aj, j)                                                     \
        { __half2* d = (__half2*)(h1out + (size_t)(sbeg + pg * 8 + j) * 128 + c); \
          d[0] = __floats2half2_rn(Aj.x, Aj.y);                               \
          d[1] = __floats2half2_rn(Aj.z, Aj.w); }
      H1ST(A0, 0) H1ST(A1, 1) H1ST(A2, 2) H1ST(A3, 3)
      H1ST(A4, 4) H1ST(A5, 5) H1ST(A6, 6) H1ST(A7, 7)
      #undef H1ST
    }
    sd0 += (double)A0.x + (double)A1.x + (double)A2.x + (double)A3.x
         + (double)A4.x + (double)A5.x + (double)A6.x + (double)A7.x;
    sd1 += (double)A0.y + (double)A1.y + (double)A2.y + (double)A3.y
         + (double)A4.y + (double)A5.y + (double)A6.y + (double)A7.y;
    sd2 += (double)A0.z + (double)A1.z + (double)A2.z + (double)A3.z
         + (double)A4.z + (double)A5.z + (double)A6.z + (double)A7.z;
    sd3 += (double)A0.w + (double)A1.w + (double)A2.w + (double)A3.w
         + (double)A4.w + (double)A5.w + (double)A6.w + (double)A7.w;
    qd0 += (double)A0.x*A0.x + (double)A1.x*A1.x + (double)A2.x*A2.x + (double)A3.x*A3.x
         + (double)A4.x*A4.x + (double)A5.x*A5.x + (double)A6.x*A6.x + (double)A7.x*A7.x;
    qd1 += (double)A0.y*A0.y + (double)A1.y*A1.y + (double)A2.y*A2.y + (double)A3.y*A3.y
         + (double)A4.y*A4.y + (double)A5.y*A5.y + (double)A6.y*A6.y + (double)A7.y*A7.y;
    qd2 += (double)A0.z*A0.z + (double)A1.z*A1.z + (double)A2.z*A2.z + (double)A3.z*A3.z
         + (double)A4.z*A4.z + (double)A5.z*A5.z + (double)A6.z*A6.z + (double)A7.z*A7.z;
    qd3 += (double)A0.w*A0.w + (double)A1.w*A1.w + (double)A2.w*A2.w + (double)A3.w*A3.w
         + (double)A4.w*A4.w + (double)A5.w*A5.w + (double)A6.w*A6.w + (double)A7.w*A7.w;
    __syncthreads();
  }

  // reduce: alias stats arrays onto the (now idle) tile buffer
  int c = cb * 4;
  sm.b.lsum[pg * 128 + c + 0] = sd0;  sm.b.lsq[pg * 128 + c + 0] = qd0;
  sm.b.lsum[pg * 128 + c + 1] = sd1;  sm.b.lsq[pg * 128 + c + 1] = qd1;
  sm.b.lsum[pg * 128 + c + 2] = sd2;  sm.b.lsq[pg * 128 + c + 2] = qd2;
  sm.b.lsum[pg * 128 + c + 3] = sd3;  sm.b.lsq[pg * 128 + c + 3] = qd3;
  __syncthreads();
  if (t < 128) {
    double S = 0, Q = 0;
    #pragma unroll
    for (int j = 0; j < 8; ++j) { S += sm.b.lsum[j * 128 + t]; Q += sm.b.lsq[j * 128 + t]; }
    atomicAdd(&gs[t], S);
    atomicAdd(&gq[t], Q);
  }
}

// ---------------- fast final: read h1, BN+ReLU, segmented max ----------------
__global__ __launch_bounds__(128) void final_cheap(
    const unsigned int* __restrict__ vsort,
    const unsigned int* __restrict__ voxloc, const unsigned int* __restrict__ bexc,
    const float* __restrict__ vcnt, const __half* __restrict__ h1,
    const float* __restrict__ sc1, const float* __restrict__ sh1,
    float* __restrict__ outp) {
  int t = threadIdx.x;               // channel 0..127
  unsigned int sbeg = blockIdx.x * STRETCH;
  float s = sc1[t], b = sh1[t];
  int curv = -1; float curm = 0.f;
  for (int i = 0; i < STRETCH; ++i) {
    int v = (int)vsort[sbeg + i];
    float h = __half2float(h1[(size_t)(sbeg + i) * 128 + t]);
    float val = fmaxf(fmaf(h, s, b), 0.f);
    if (v != curv) {
      if (curv >= 0) {
        unsigned int vstart = voxloc[curv] + bexc[curv >> 8];
        unsigned int n = (unsigned int)vcnt[curv];
        if (vstart >= sbeg && vstart + n <= sbeg + STRETCH)
          outp[(size_t)curv * 128 + t] = curm;
        else
          atomicMax((unsigned int*)&outp[(size_t)curv * 128 + t],
                    __float_as_uint(curm));
      }
      curv = v;
      curm = val;
    } else {
      curm = fmaxf(curm, val);
    }
  }
  if (curv >= 0) {
    unsigned int vstart = voxloc[curv] + bexc[curv >> 8];
    unsigned int n = (unsigned int)vcnt[curv];
    if (vstart >= sbeg && vstart + n <= sbeg + STRETCH)
      outp[(size_t)curv * 128 + t] = curm;
    else
      atomicMax((unsigned int*)&outp[(size_t)curv * 128 + t],
                __float_as_uint(curm));
  }
}

// ---------------- fallback final (R12 verbatim) ----------------
__global__ __launch_bounds__(256) void final2(const float* __restrict__ pts,
    const float* __restrict__ vcnt, const float* __restrict__ vsx,
    const float* __restrict__ vsy, const float* __restrict__ vsz,
    const unsigned int* __restrict__ voxloc, const unsigned int* __restrict__ bexc,
    const unsigned int* __restrict__ plist,
    const float* __restrict__ W0, const float* __restrict__ sc0,
    const float* __restrict__ sh0, const float* __restrict__ vmax,
    const float* __restrict__ W1, const float* __restrict__ sc1,
    const float* __restrict__ sh1, float* __restrict__ outp) {
  __shared__ float sf[STRETCH][12];
  __shared__ int   svid[STRETCH];
  __shared__ float sfeat[STRETCH][128];

  int t = threadIdx.x;
  int pg = t >> 5, cb = t & 31;
  unsigned int sbeg = blockIdx.x * STRETCH;

  TILE_STAGE(sbeg)
  TILE_GEMM()
  __syncthreads();

  int c = cb * 4;
  float4 s1v = *reinterpret_cast<const float4*>(sc1 + c);
  float4 h1v = *reinterpret_cast<const float4*>(sh1 + c);
  #define BNST(Aj, j)                                                        \
    { float4 P;                                                              \
      P.x = fmaxf(fmaf(Aj.x, s1v.x, h1v.x), 0.f);                            \
      P.y = fmaxf(fmaf(Aj.y, s1v.y, h1v.y), 0.f);                            \
      P.z = fmaxf(fmaf(Aj.z, s1v.z, h1v.z), 0.f);                            \
      P.w = fmaxf(fmaf(Aj.w, s1v.w, h1v.w), 0.f);                            \
      *reinterpret_cast<float4*>(&sfeat[pg * 8 + j][c]) = P; }
  BNST(A0, 0) BNST(A1, 1) BNST(A2, 2) BNST(A3, 3)
  BNST(A4, 4) BNST(A5, 5) BNST(A6, 6) BNST(A7, 7)
  #undef BNST
  __syncthreads();

  if (t < 128) {
    int curv = -1; float curm = 0.f;
    for (int i = 0; i < STRETCH; ++i) {
      int v = svid[i];
      if (v != curv) {
        if (curv >= 0) {
          unsigned int vstart = voxloc[curv] + bexc[curv >> 8];
          unsigned int n = (unsigned int)vcnt[curv];
          if (vstart >= sbeg && vstart + n <= sbeg + STRETCH)
            outp[(size_t)curv * 128 + t] = curm;
          else
            atomicMax((unsigned int*)&outp[(size_t)curv * 128 + t],
                      __float_as_uint(curm));
        }
        curv = v;
        curm = sfeat[i][t];
      } else {
        curm = fmaxf(curm, sfeat[i][t]);
      }
    }
    if (curv >= 0) {
      unsigned int vstart = voxloc[curv] + bexc[curv >> 8];
      unsigned int n = (unsigned int)vcnt[curv];
      if (vstart >= sbeg && vstart + n <= sbeg + STRETCH)
        outp[(size_t)curv * 128 + t] = curm;
      else
        atomicMax((unsigned int*)&outp[(size_t)curv * 128 + t],
                  __float_as_uint(curm));
    }
  }
}

extern "C" void kernel_launch(void* const* d_in, const int* in_sizes, int n_in,
                              void* d_out, int out_size, void* d_ws, size_t ws_size,
                              hipStream_t stream) {
  const float* pts = (const float*)d_in[0];
  const float* W0  = (const float*)d_in[1];
  const float* g0  = (const float*)d_in[2];
  const float* b0  = (const float*)d_in[3];
  const float* W1  = (const float*)d_in[4];
  const float* g1  = (const float*)d_in[5];
  const float* b1  = (const float*)d_in[6];

  char* base = (char*)d_ws;
  double* stats = (double*)base;
  float*  fold  = (float*)(base + 3072);
  float*  vcnt  = (float*)(base + 4608);
  float*  vsx   = vcnt + NVOX;
  float*  vsy   = vsx + NVOX;
  float*  vsz   = vsy + NVOX;
  float*  vmax  = vsz + NVOX;                          // NVOX*64 f32 (72MB)
  unsigned int* voxloc = (unsigned int*)(vmax + (size_t)NVOX * 64);
  unsigned int* cursor = voxloc + NVOX;
  unsigned int* plist  = cursor + NVOX;
  unsigned int* vsort  = plist + NPTS;
  unsigned int* bsum   = vsort + NPTS;
  unsigned int* bexc   = bsum + SCANB;
  __half* h1 = (__half*)(bexc + SCANB);
  size_t need_fast = (size_t)((char*)h1 - base) + (size_t)NPTS * 128 * sizeof(__half);
  bool fast = ws_size >= need_fast;

  double* s0 = stats,       *q0 = stats + 64;
  double* s1 = stats + 128, *q1 = stats + 256;
  float* sc0 = fold,       *sh0 = fold + 64;
  float* sc1 = fold + 128, *sh1 = fold + 256;

  hipMemsetAsync(stats, 0, 3072, stream);
  hipMemsetAsync(vcnt, 0, (size_t)4 * NVOX * sizeof(float), stream);
  hipMemsetAsync(vmax, 0, (size_t)NVOX * 64 * sizeof(float), stream);
  hipMemsetAsync(cursor, 0, (size_t)NVOX * sizeof(unsigned int), stream);
  hipMemsetAsync(d_out, 0, (size_t)out_size * sizeof(float), stream);

  voxsum<<<NBLK, TPB, 0, stream>>>(pts, vcnt, vsx, vsy, vsz);
  scan1<<<SCANB, 256, 0, stream>>>(vcnt, voxloc, bsum);
  scan2<<<1, 64, 0, stream>>>(bsum, bexc);
  scatter<<<NBLK, TPB, 0, stream>>>(pts, voxloc, bexc, cursor, plist, vsort);
  bn0stats<<<NBLK, TPB, 0, stream>>>(pts, vcnt, vsx, vsy, vsz, W0, s0, q0);
  bnfold<<<1, 64, 0, stream>>>(s0, q0, g0, b0, sc0, sh0, 64);
  vmax0_stretch<<<FBLK, TPB, 0, stream>>>(pts, vcnt, vsx, vsy, vsz, voxloc, bexc,
                                          plist, W0, sc0, sh0, vmax);
  if (fast) {
    gemm1s<1><<<SBLK2, TPB, 0, stream>>>(pts, vcnt, vsx, vsy, vsz, plist,
                                         W0, sc0, sh0, vmax, W1, s1, q1, h1);
    bnfold<<<1, 128, 0, stream>>>(s1, q1, g1, b1, sc1, sh1, 128);
    final_cheap<<<FBLK, 128, 0, stream>>>(vsort, voxloc, bexc, vcnt, h1,
                                          sc1, sh1, (float*)d_out);
  } else {
    gemm1s<0><<<SBLK2, TPB, 0, stream>>>(pts, vcnt, vsx, vsy, vsz, plist,
                                         W0, sc0, sh0, vmax, W1, s1, q1, nullptr);
    bnfold<<<1, 128, 0, stream>>>(s1, q1, g1, b1, sc1, sh1, 128);
    final2<<<FBLK, TPB, 0, stream>>>(pts, vcnt, vsx, vsy, vsz, voxloc, bexc,
                                     plist, W0, sc0, sh0, vmax, W1, sc1, sh1,
                                     (float*)d_out);
  }
}

// Round 14
// 459.507 us; speedup vs baseline: 10.5824x; 1.3446x over previous
//
#include <hip/hip_runtime.h>
#include <hip/hip_fp16.h>
#include <stdint.h>

#define NPTS 400000
#define NVOX 281600
#define TPB  256
#define NBLK ((NPTS + TPB - 1) / TPB)
#define SCANB (NVOX / 256)       // 1100 exact
#define STRETCH 64
#define FBLK (NPTS / STRETCH)    // 6250 exact
#define SBLK2 1024

typedef _Float16 h8  __attribute__((ext_vector_type(8)));
typedef _Float16 h4v __attribute__((ext_vector_type(4)));
typedef float    f4  __attribute__((ext_vector_type(4)));

// XLA-style binning: division folded to multiply-by-reciprocal in f32.
// DO NOT CHANGE: exactly matches the golden (round 6->7 proof).
__device__ __forceinline__ int bin3(const float* __restrict__ pt,
                                    int& bx, int& by, int& bz) {
  float x = pt[1], y = pt[2], z = pt[3];
  bx = (int)fminf(fmaxf(floorf(x * 5.0f), 0.f), 351.f);
  by = (int)fminf(fmaxf(floorf((y + 40.f) * 5.0f), 0.f), 399.f);
  bz = (int)fminf(fmaxf(floorf((z + 3.f) * 0.25f), 0.f), 0.f);
  return (((int)pt[0] + bz) * 400 + by) * 352 + bx;
}

__device__ __forceinline__ int mkfeat(const float* __restrict__ pt,
    const float* __restrict__ vcnt, const float* __restrict__ vsx,
    const float* __restrict__ vsy, const float* __restrict__ vsz,
    float* f) {
  int bx, by, bz;
  int v = bin3(pt, bx, by, bz);
  float x = pt[1], y = pt[2], z = pt[3];
  float n = fmaxf(vcnt[v], 1.f);
  f[0] = x;  f[1] = y;  f[2] = z;  f[3] = pt[4];
  f[4] = x - vsx[v] / n;
  f[5] = y - vsy[v] / n;
  f[6] = z - vsz[v] / n;
  f[7] = x - (0.2f * (float)bx + 0.1f);
  f[8] = y - (0.2f * (float)by - 39.9f);
  f[9] = z - (4.0f * (float)bz - 1.0f);
  return v;
}

// ---------------- prologue ----------------
__global__ __launch_bounds__(256) void voxsum(const float* __restrict__ pts,
    float* __restrict__ vcnt, float* __restrict__ vsx,
    float* __restrict__ vsy, float* __restrict__ vsz) {
  int p = blockIdx.x * TPB + threadIdx.x;
  if (p >= NPTS) return;
  const float* pt = pts + (size_t)p * 5;
  int bx, by, bz;
  int v = bin3(pt, bx, by, bz);
  atomicAdd(&vcnt[v], 1.f);
  atomicAdd(&vsx[v], pt[1]);
  atomicAdd(&vsy[v], pt[2]);
  atomicAdd(&vsz[v], pt[3]);
}

__global__ __launch_bounds__(256) void bn0stats(const float* __restrict__ pts,
    const float* __restrict__ vcnt, const float* __restrict__ vsx,
    const float* __restrict__ vsy, const float* __restrict__ vsz,
    const float* __restrict__ W0,
    double* __restrict__ gs, double* __restrict__ gq) {
  __shared__ float bs[4][64], bq[4][64];
  int t = threadIdx.x, wv = t >> 6, ln = t & 63;
  int p = blockIdx.x * TPB + t;
  bool ok = p < NPTS;
  const float* pt = pts + (size_t)(ok ? p : 0) * 5;
  float f[10];
  mkfeat(pt, vcnt, vsx, vsy, vsz, f);
  for (int c = 0; c < 64; ++c) {
    float h = f[0] * W0[c];
    #pragma unroll
    for (int i = 1; i < 10; ++i) h = fmaf(f[i], W0[i * 64 + c], h);
    h = ok ? h : 0.f;
    float q = h * h;
    #pragma unroll
    for (int m = 1; m < 64; m <<= 1) {
      h += __shfl_xor(h, m, 64);
      q += __shfl_xor(q, m, 64);
    }
    if (ln == 0) { bs[wv][c] = h; bq[wv][c] = q; }
  }
  __syncthreads();
  if (t < 64) {
    atomicAdd(&gs[t], (double)bs[0][t] + bs[1][t] + bs[2][t] + bs[3][t]);
    atomicAdd(&gq[t], (double)bq[0][t] + bq[1][t] + bq[2][t] + bq[3][t]);
  }
}

__global__ void bnfold(const double* __restrict__ gs, const double* __restrict__ gq,
                       const float* __restrict__ gam, const float* __restrict__ bet,
                       float* __restrict__ sc, float* __restrict__ sh, int C) {
  int c = threadIdx.x;
  if (c >= C) return;
  double mu  = gs[c] / (double)NPTS;
  double var = gq[c] / (double)NPTS - mu * mu;
  double s = (double)gam[c] / sqrt(var + 1e-3);
  sc[c] = (float)s;
  sh[c] = (float)((double)bet[c] - mu * s);
}

// ---------------- counting sort ----------------
__global__ __launch_bounds__(256) void scan1(const float* __restrict__ vcnt,
    unsigned int* __restrict__ voxloc, unsigned int* __restrict__ bsum) {
  __shared__ unsigned int s[256];
  int t = threadIdx.x;
  int i = blockIdx.x * 256 + t;
  unsigned int val = (unsigned int)vcnt[i];
  s[t] = val;
  __syncthreads();
  for (int off = 1; off < 256; off <<= 1) {
    unsigned int add = (t >= off) ? s[t - off] : 0u;
    __syncthreads();
    s[t] += add;
    __syncthreads();
  }
  voxloc[i] = s[t] - val;
  if (t == 255) bsum[blockIdx.x] = s[t];
}

__global__ void scan2(const unsigned int* __restrict__ bsum,
                      unsigned int* __restrict__ bexc) {
  if (threadIdx.x != 0) return;
  unsigned int run = 0;
  for (int b = 0; b < SCANB; ++b) { bexc[b] = run; run += bsum[b]; }
}

__global__ __launch_bounds__(256) void scatter(const float* __restrict__ pts,
    const unsigned int* __restrict__ voxloc, const unsigned int* __restrict__ bexc,
    unsigned int* __restrict__ cursor, unsigned int* __restrict__ plist,
    unsigned int* __restrict__ vsort) {
  int p = blockIdx.x * TPB + threadIdx.x;
  if (p >= NPTS) return;
  int bx, by, bz;
  int v = bin3(pts + (size_t)p * 5, bx, by, bz);
  unsigned int pos = voxloc[v] + bexc[v >> 8] + atomicAdd(&cursor[v], 1u);
  plist[pos] = (unsigned int)p;
  vsort[pos] = (unsigned int)v;
}

// ---------------- vmax0 over sorted stretches ----------------
__global__ __launch_bounds__(256) void vmax0_stretch(const float* __restrict__ pts,
    const float* __restrict__ vcnt, const float* __restrict__ vsx,
    const float* __restrict__ vsy, const float* __restrict__ vsz,
    const unsigned int* __restrict__ voxloc, const unsigned int* __restrict__ bexc,
    const unsigned int* __restrict__ plist,
    const float* __restrict__ W0, const float* __restrict__ sc0,
    const float* __restrict__ sh0, float* __restrict__ vmax) {
  __shared__ float sf[STRETCH][12];
  __shared__ int   svid[STRETCH];
  __shared__ float pf[STRETCH][64];
  int t = threadIdx.x;
  unsigned int sbeg = blockIdx.x * STRETCH;

  if (t < STRETCH) {
    unsigned int pidx = plist[sbeg + t];
    svid[t] = mkfeat(pts + (size_t)pidx * 5, vcnt, vsx, vsy, vsz, &sf[t][0]);
  }
  __syncthreads();
  for (int idx = t; idx < STRETCH * 64; idx += TPB) {
    int pt_ = idx >> 6, k = idx & 63;
    float h = sf[pt_][0] * W0[k];
    #pragma unroll
    for (int i = 1; i < 10; ++i) h = fmaf(sf[pt_][i], W0[i * 64 + k], h);
    pf[pt_][k] = fmaxf(fmaf(h, sc0[k], sh0[k]), 0.f);
  }
  __syncthreads();

  if (t < 64) {
    int curv = -1; float curm = 0.f;
    for (int i = 0; i < STRETCH; ++i) {
      int v = svid[i];
      if (v != curv) {
        if (curv >= 0) {
          unsigned int vstart = voxloc[curv] + bexc[curv >> 8];
          unsigned int n = (unsigned int)vcnt[curv];
          if (vstart >= sbeg && vstart + n <= sbeg + STRETCH)
            vmax[(size_t)curv * 64 + t] = curm;
          else
            atomicMax((unsigned int*)&vmax[(size_t)curv * 64 + t],
                      __float_as_uint(curm));
        }
        curv = v;
        curm = pf[i][t];
      } else {
        curm = fmaxf(curm, pf[i][t]);
      }
    }
    if (curv >= 0) {
      unsigned int vstart = voxloc[curv] + bexc[curv >> 8];
      unsigned int n = (unsigned int)vcnt[curv];
      if (vstart >= sbeg && vstart + n <= sbeg + STRETCH)
        vmax[(size_t)curv * 64 + t] = curm;
      else
        atomicMax((unsigned int*)&vmax[(size_t)curv * 64 + t],
                  __float_as_uint(curm));
    }
  }
}

// ---------------- W1 -> fragment-ordered fp16 ----------------
// Wf[(ntile*4+ks)*64 + l][j] = W1[k][n], n = ntile*16 + (l&15),
// k = ks*32 + (j>>2)*16 + 4*(l>>4) + (j&3)   (canonical f16 MFMA B layout)
__global__ __launch_bounds__(256) void wconv(const float* __restrict__ W1,
                                             _Float16* __restrict__ Wf) {
  int idx = blockIdx.x * 256 + threadIdx.x;
  if (idx >= 32 * 64 * 8) return;
  int j = idx & 7, l = (idx >> 3) & 63, f = idx >> 9;
  int ks = f & 3, ntile = f >> 2;
  int k = ks * 32 + ((j >> 2) * 16) + 4 * (l >> 4) + (j & 3);
  int n = ntile * 16 + (l & 15);
  Wf[idx] = (_Float16)W1[k * 128 + n];
}

// ---------------- MFMA layer-1: stats + h1(fp16) in one pass ----------------
__device__ __forceinline__ h8 lda(const _Float16* __restrict__ r, int k0) {
  h4v lo = *(const h4v*)(r + k0);
  h4v hi = *(const h4v*)(r + k0 + 16);
  h8 a;
  a[0] = lo[0]; a[1] = lo[1]; a[2] = lo[2]; a[3] = lo[3];
  a[4] = hi[0]; a[5] = hi[1]; a[6] = hi[2]; a[7] = hi[3];
  return a;
}

__device__ __forceinline__ void emit_tile(f4 C, int ptb, int ch,
    _Float16* __restrict__ h1o, float& sf_, float& qf_) {
  float v0 = C[0], v1 = C[1], v2 = C[2], v3 = C[3];
  h1o[(size_t)(ptb + 0) * 128 + ch] = (_Float16)v0;
  h1o[(size_t)(ptb + 1) * 128 + ch] = (_Float16)v1;
  h1o[(size_t)(ptb + 2) * 128 + ch] = (_Float16)v2;
  h1o[(size_t)(ptb + 3) * 128 + ch] = (_Float16)v3;
  sf_ += (v0 + v1) + (v2 + v3);
  qf_ = fmaf(v0, v0, fmaf(v1, v1, fmaf(v2, v2, fmaf(v3, v3, qf_))));
}

__global__ __launch_bounds__(256) void gemm1m(const float* __restrict__ pts,
    const float* __restrict__ vcnt, const float* __restrict__ vsx,
    const float* __restrict__ vsy, const float* __restrict__ vsz,
    const unsigned int* __restrict__ plist,
    const float* __restrict__ W0, const float* __restrict__ sc0,
    const float* __restrict__ sh0, const float* __restrict__ vmax,
    const _Float16* __restrict__ Wf,
    double* __restrict__ gs, double* __restrict__ gq,
    _Float16* __restrict__ h1out) {
  __shared__ float sf[STRETCH][12];
  __shared__ int   svid[STRETCH];
  __shared__ __align__(16) _Float16 fh[64][140];   // 280B rows: <=2-way banks

  int t = threadIdx.x;
  int w = t >> 6, l = t & 63;
  int lm = l & 15, lg = l >> 4;

  // persistent B fragments (2 nt x 4 ks), one coalesced 16B load each
  const h8* wfv = (const h8*)Wf;
  h8 B00 = wfv[((w * 2 + 0) * 4 + 0) * 64 + l];
  h8 B01 = wfv[((w * 2 + 0) * 4 + 1) * 64 + l];
  h8 B02 = wfv[((w * 2 + 0) * 4 + 2) * 64 + l];
  h8 B03 = wfv[((w * 2 + 0) * 4 + 3) * 64 + l];
  h8 B10 = wfv[((w * 2 + 1) * 4 + 0) * 64 + l];
  h8 B11 = wfv[((w * 2 + 1) * 4 + 1) * 64 + l];
  h8 B12 = wfv[((w * 2 + 1) * 4 + 2) * 64 + l];
  h8 B13 = wfv[((w * 2 + 1) * 4 + 3) * 64 + l];

  double sd0 = 0, sd1 = 0, qd0 = 0, qd1 = 0;

  for (int tile = blockIdx.x; tile < FBLK; tile += gridDim.x) {
    unsigned int sbeg = tile * STRETCH;
    if (t < STRETCH) {
      unsigned int pidx = plist[sbeg + t];
      svid[t] = mkfeat(pts + (size_t)pidx * 5, vcnt, vsx, vsy, vsz, &sf[t][0]);
    }
    __syncthreads();
    for (int idx = t; idx < STRETCH * 64; idx += TPB) {
      int p_ = idx >> 6, k = idx & 63;
      float h = sf[p_][0] * W0[k];
      #pragma unroll
      for (int i = 1; i < 10; ++i) h = fmaf(sf[p_][i], W0[i * 64 + k], h);
      fh[p_][k] = (_Float16)fmaxf(fmaf(h, sc0[k], sh0[k]), 0.f);
    }
    for (int idx = t; idx < STRETCH * 64; idx += TPB) {
      int p_ = idx >> 6, k = idx & 63;
      fh[p_][64 + k] = (_Float16)vmax[(size_t)svid[p_] * 64 + k];
    }
    __syncthreads();

    f4 C00 = {0,0,0,0}, C01 = {0,0,0,0}, C10 = {0,0,0,0}, C11 = {0,0,0,0};
    f4 C20 = {0,0,0,0}, C21 = {0,0,0,0}, C30 = {0,0,0,0}, C31 = {0,0,0,0};

    #define DO_MT(mt, CA, CB) {                                              \
      const _Float16* r = &fh[(mt) * 16 + lm][0];                            \
      h8 A0 = lda(r, 0 * 32 + 4 * lg);                                       \
      h8 A1 = lda(r, 1 * 32 + 4 * lg);                                       \
      h8 A2 = lda(r, 2 * 32 + 4 * lg);                                       \
      h8 A3 = lda(r, 3 * 32 + 4 * lg);                                       \
      CA = __builtin_amdgcn_mfma_f32_16x16x32_f16(A0, B00, CA, 0, 0, 0);     \
      CA = __builtin_amdgcn_mfma_f32_16x16x32_f16(A1, B01, CA, 0, 0, 0);     \
      CA = __builtin_amdgcn_mfma_f32_16x16x32_f16(A2, B02, CA, 0, 0, 0);     \
      CA = __builtin_amdgcn_mfma_f32_16x16x32_f16(A3, B03, CA, 0, 0, 0);     \
      CB = __builtin_amdgcn_mfma_f32_16x16x32_f16(A0, B10, CB, 0, 0, 0);     \
      CB = __builtin_amdgcn_mfma_f32_16x16x32_f16(A1, B11, CB, 0, 0, 0);     \
      CB = __builtin_amdgcn_mfma_f32_16x16x32_f16(A2, B12, CB, 0, 0, 0);     \
      CB = __builtin_amdgcn_mfma_f32_16x16x32_f16(A3, B13, CB, 0, 0, 0); }
    DO_MT(0, C00, C01)
    DO_MT(1, C10, C11)
    DO_MT(2, C20, C21)
    DO_MT(3, C30, C31)
    #undef DO_MT

    // h1 store + stats (C/D layout: row=(l>>4)*4+reg, col=l&15 — m89-verified)
    float s0f = 0, q0f = 0, s1f = 0, q1f = 0;
    int ch0 = w * 32 + lm, ch1 = w * 32 + 16 + lm;
    emit_tile(C00, sbeg + 0 * 16 + lg * 4, ch0, h1out, s0f, q0f);
    emit_tile(C01, sbeg + 0 * 16 + lg * 4, ch1, h1out, s1f, q1f);
    emit_tile(C10, sbeg + 1 * 16 + lg * 4, ch0, h1out, s0f, q0f);
    emit_tile(C11, sbeg + 1 * 16 + lg * 4, ch1, h1out, s1f, q1f);
    emit_tile(C20, sbeg + 2 * 16 + lg * 4, ch0, h1out, s0f, q0f);
    emit_tile(C21, sbeg + 2 * 16 + lg * 4, ch1, h1out, s1f, q1f);
    emit_tile(C30, sbeg + 3 * 16 + lg * 4, ch0, h1out, s0f, q0f);
    emit_tile(C31, sbeg + 3 * 16 + lg * 4, ch1, h1out, s1f, q1f);
    sd0 += (double)s0f; qd0 += (double)q0f;
    sd1 += (double)s1f; qd1 += (double)q1f;
    __syncthreads();   // protect fh before next tile's staging
  }

  // cross-lane stats reduce: lanes l, l^16, l^32, l^48 share a channel
  sd0 += __shfl_xor(sd0, 16, 64); sd0 += __shfl_xor(sd0, 32, 64);
  qd0 += __shfl_xor(qd0, 16, 64); qd0 += __shfl_xor(qd0, 32, 64);
  sd1 += __shfl_xor(sd1, 16, 64); sd1 += __shfl_xor(sd1, 32, 64);
  qd1 += __shfl_xor(qd1, 16, 64); qd1 += __shfl_xor(qd1, 32, 64);
  if (lg == 0) {
    atomicAdd(&gs[w * 32 + lm], sd0);
    atomicAdd(&gq[w * 32 + lm], qd0);
    atomicAdd(&gs[w * 32 + 16 + lm], sd1);
    atomicAdd(&gq[w * 32 + 16 + lm], qd1);
  }
}

// ---------------- fast final: read h1, BN+ReLU, segmented max ----------------
__global__ __launch_bounds__(128) void final_cheap(
    const unsigned int* __restrict__ vsort,
    const unsigned int* __restrict__ voxloc, const unsigned int* __restrict__ bexc,
    const float* __restrict__ vcnt, const __half* __restrict__ h1,
    const float* __restrict__ sc1, const float* __restrict__ sh1,
    float* __restrict__ outp) {
  int t = threadIdx.x;
  unsigned int sbeg = blockIdx.x * STRETCH;
  float s = sc1[t], b = sh1[t];
  int curv = -1; float curm = 0.f;
  for (int i = 0; i < STRETCH; ++i) {
    int v = (int)vsort[sbeg + i];
    float h = __half2float(h1[(size_t)(sbeg + i) * 128 + t]);
    float val = fmaxf(fmaf(h, s, b), 0.f);
    if (v != curv) {
      if (curv >= 0) {
        unsigned int vstart = voxloc[curv] + bexc[curv >> 8];
        unsigned int n = (unsigned int)vcnt[curv];
        if (vstart >= sbeg && vstart + n <= sbeg + STRETCH)
          outp[(size_t)curv * 128 + t] = curm;
        else
          atomicMax((unsigned int*)&outp[(size_t)curv * 128 + t],
                    __float_as_uint(curm));
      }
      curv = v;
      curm = val;
    } else {
      curm = fmaxf(curm, val);
    }
  }
  if (curv >= 0) {
    unsigned int vstart = voxloc[curv] + bexc[curv >> 8];
    unsigned int n = (unsigned int)vcnt[curv];
    if (vstart >= sbeg && vstart + n <= sbeg + STRETCH)
      outp[(size_t)curv * 128 + t] = curm;
    else
      atomicMax((unsigned int*)&outp[(size_t)curv * 128 + t],
                __float_as_uint(curm));
  }
}

// ---------------- fp32 fallback path (R13 verbatim, proven) ----------------
#define TILE_STAGE(sbeg_)                                                    \
  if (t < STRETCH) {                                                         \
    unsigned int pidx = plist[(sbeg_) + t];                                  \
    svid[t] = mkfeat(pts + (size_t)pidx * 5, vcnt, vsx, vsy, vsz, &sf[t][0]);\
  }                                                                          \
  __syncthreads();                                                           \
  for (int idx = t; idx < STRETCH * 64; idx += TPB) {                        \
    int pt_ = idx >> 6, k = idx & 63;                                        \
    float h = sf[pt_][0] * W0[k];                                            \
    _Pragma("unroll")                                                        \
    for (int i = 1; i < 10; ++i) h = fmaf(sf[pt_][i], W0[i * 64 + k], h);    \
    sfeat[pt_][k] = fmaxf(fmaf(h, sc0[k], sh0[k]), 0.f);                     \
  }                                                                          \
  for (int idx = t; idx < STRETCH * 64; idx += TPB) {                        \
    int pt_ = idx >> 6, k = idx & 63;                                        \
    sfeat[pt_][64 + k] = vmax[(size_t)svid[pt_] * 64 + k];                   \
  }                                                                          \
  __syncthreads();

#define TILE_GEMM()                                                          \
  const float* r0 = sfeat[pg * 8 + 0];                                       \
  const float* r1 = sfeat[pg * 8 + 1];                                       \
  const float* r2 = sfeat[pg * 8 + 2];                                       \
  const float* r3 = sfeat[pg * 8 + 3];                                       \
  const float* r4 = sfeat[pg * 8 + 4];                                       \
  const float* r5 = sfeat[pg * 8 + 5];                                       \
  const float* r6 = sfeat[pg * 8 + 6];                                       \
  const float* r7 = sfeat[pg * 8 + 7];                                       \
  float4 A0 = {0,0,0,0}, A1 = {0,0,0,0}, A2 = {0,0,0,0}, A3 = {0,0,0,0};     \
  float4 A4 = {0,0,0,0}, A5 = {0,0,0,0}, A6 = {0,0,0,0}, A7 = {0,0,0,0};     \
  _Pragma("unroll 8")                                                        \
  for (int k = 0; k < 128; ++k) {                                            \
    float4 w = *reinterpret_cast<const float4*>(W1 + (size_t)k * 128 + cb*4);\
    float p0 = r0[k], p1_ = r1[k], p2 = r2[k], p3 = r3[k];                   \
    float p4 = r4[k], p5 = r5[k], p6 = r6[k], p7 = r7[k];                    \
    A0.x = fmaf(p0, w.x, A0.x); A0.y = fmaf(p0, w.y, A0.y);                  \
    A0.z = fmaf(p0, w.z, A0.z); A0.w = fmaf(p0, w.w, A0.w);                  \
    A1.x = fmaf(p1_, w.x, A1.x); A1.y = fmaf(p1_, w.y, A1.y);                \
    A1.z = fmaf(p1_, w.z, A1.z); A1.w = fmaf(p1_, w.w, A1.w);                \
    A2.x = fmaf(p2, w.x, A2.x); A2.y = fmaf(p2, w.y, A2.y);                  \
    A2.z = fmaf(p2, w.z, A2.z); A2.w = fmaf(p2, w.w, A2.w);                  \
    A3.x = fmaf(p3, w.x, A3.x); A3.y = fmaf(p3, w.y, A3.y);                  \
    A3.z = fmaf(p3, w.z, A3.z); A3.w = fmaf(p3, w.w, A3.w);                  \
    A4.x = fmaf(p4, w.x, A4.x); A4.y = fmaf(p4, w.y, A4.y);                  \
    A4.z = fmaf(p4, w.z, A4.z); A4.w = fmaf(p4, w.w, A4.w);                  \
    A5.x = fmaf(p5, w.x, A5.x); A5.y = fmaf(p5, w.y, A5.y);                  \
    A5.z = fmaf(p5, w.z, A5.z); A5.w = fmaf(p5, w.w, A5.w);                  \
    A6.x = fmaf(p6, w.x, A6.x); A6.y = fmaf(p6, w.y, A6.y);                  \
    A6.z = fmaf(p6, w.z, A6.z); A6.w = fmaf(p6, w.w, A6.w);                  \
    A7.x = fmaf(p7, w.x, A7.x); A7.y = fmaf(p7, w.y, A7.y);                  \
    A7.z = fmaf(p7, w.z, A7.z); A7.w = fmaf(p7, w.w, A7.w);                  \
  }

__global__ __launch_bounds__(256) void gemm1s_f32(const float* __restrict__ pts,
    const float* __restrict__ vcnt, const float* __restrict__ vsx,
    const float* __restrict__ vsy, const float* __restrict__ vsz,
    const unsigned int* __restrict__ plist,
    const float* __restrict__ W0, const float* __restrict__ sc0,
    const float* __restrict__ sh0, const float* __restrict__ vmax,
    const float* __restrict__ W1,
    double* __restrict__ gs, double* __restrict__ gq) {
  union SM {
    struct { float sf[STRETCH][12]; int svid[STRETCH]; float sfeat[STRETCH][128]; } a;
    struct { double lsum[8 * 128]; double lsq[8 * 128]; } b;
  };
  __shared__ SM sm;
  auto& sf = sm.a.sf;
  auto& svid = sm.a.svid;
  auto& sfeat = sm.a.sfeat;

  int t = threadIdx.x;
  int pg = t >> 5, cb = t & 31;
  double sd0 = 0, sd1 = 0, sd2 = 0, sd3 = 0;
  double qd0 = 0, qd1 = 0, qd2 = 0, qd3 = 0;

  for (int tile = blockIdx.x; tile < FBLK; tile += gridDim.x) {
    unsigned int sbeg = tile * STRETCH;
    TILE_STAGE(sbeg)
    TILE_GEMM()
    sd0 += (double)A0.x + (double)A1.x + (double)A2.x + (double)A3.x
         + (double)A4.x + (double)A5.x + (double)A6.x + (double)A7.x;
    sd1 += (double)A0.y + (double)A1.y + (double)A2.y + (double)A3.y
         + (double)A4.y + (double)A5.y + (double)A6.y + (double)A7.y;
    sd2 += (double)A0.z + (double)A1.z + (double)A2.z + (double)A3.z
         + (double)A4.z + (double)A5.z + (double)A6.z + (double)A7.z;
    sd3 += (double)A0.w + (double)A1.w + (double)A2.w + (double)A3.w
         + (double)A4.w + (double)A5.w + (double)A6.w + (double)A7.w;
    qd0 += (double)A0.x*A0.x + (double)A1.x*A1.x + (double)A2.x*A2.x + (double)A3.x*A3.x
         + (double)A4.x*A4.x + (double)A5.x*A5.x + (double)A6.x*A6.x + (double)A7.x*A7.x;
    qd1 += (double)A0.y*A0.y + (double)A1.y*A1.y + (double)A2.y*A2.y + (double)A3.y*A3.y
         + (double)A4.y*A4.y + (double)A5.y*A5.y + (double)A6.y*A6.y + (double)A7.y*A7.y;
    qd2 += (double)A0.z*A0.z + (double)A1.z*A1.z + (double)A2.z*A2.z + (double)A3.z*A3.z
         + (double)A4.z*A4.z + (double)A5.z*A5.z + (double)A6.z*A6.z + (double)A7.z*A7.z;
    qd3 += (double)A0.w*A0.w + (double)A1.w*A1.w + (double)A2.w*A2.w + (double)A3.w*A3.w
         + (double)A4.w*A4.w + (double)A5.w*A5.w + (double)A6.w*A6.w + (double)A7.w*A7.w;
    __syncthreads();
  }

  int c = cb * 4;
  sm.b.lsum[pg * 128 + c + 0] = sd0;  sm.b.lsq[pg * 128 + c + 0] = qd0;
  sm.b.lsum[pg * 128 + c + 1] = sd1;  sm.b.lsq[pg * 128 + c + 1] = qd1;
  sm.b.lsum[pg * 128 + c + 2] = sd2;  sm.b.lsq[pg * 128 + c + 2] = qd2;
  sm.b.lsum[pg * 128 + c + 3] = sd3;  sm.b.lsq[pg * 128 + c + 3] = qd3;
  __syncthreads();
  if (t < 128) {
    double S = 0, Q = 0;
    #pragma unroll
    for (int j = 0; j < 8; ++j) { S += sm.b.lsum[j * 128 + t]; Q += sm.b.lsq[j * 128 + t]; }
    atomicAdd(&gs[t], S);
    atomicAdd(&gq[t], Q);
  }
}

__global__ __launch_bounds__(256) void final2(const float* __restrict__ pts,
    const float* __restrict__ vcnt, const float* __restrict__ vsx,
    const float* __restrict__ vsy, const float* __restrict__ vsz,
    const unsigned int* __restrict__ voxloc, const unsigned int* __restrict__ bexc,
    const unsigned int* __restrict__ plist,
    const float* __restrict__ W0, const float* __restrict__ sc0,
    const float* __restrict__ sh0, const float* __restrict__ vmax,
    const float* __restrict__ W1, const float* __restrict__ sc1,
    const float* __restrict__ sh1, float* __restrict__ outp) {
  __shared__ float sf[STRETCH][12];
  __shared__ int   svid[STRETCH];
  __shared__ float sfeat[STRETCH][128];

  int t = threadIdx.x;
  int pg = t >> 5, cb = t & 31;
  unsigned int sbeg = blockIdx.x * STRETCH;

  TILE_STAGE(sbeg)
  TILE_GEMM()
  __syncthreads();

  int c = cb * 4;
  float4 s1v = *reinterpret_cast<const float4*>(sc1 + c);
  float4 h1v = *reinterpret_cast<const float4*>(sh1 + c);
  #define BNST(Aj, j)                                                        \
    { float4 P;                                                              \
      P.x = fmaxf(fmaf(Aj.x, s1v.x, h1v.x), 0.f);                            \
      P.y = fmaxf(fmaf(Aj.y, s1v.y, h1v.y), 0.f);                            \
      P.z = fmaxf(fmaf(Aj.z, s1v.z, h1v.z), 0.f);                            \
      P.w = fmaxf(fmaf(Aj.w, s1v.w, h1v.w), 0.f);                            \
      *reinterpret_cast<float4*>(&sfeat[pg * 8 + j][c]) = P; }
  BNST(A0, 0) BNST(A1, 1) BNST(A2, 2) BNST(A3, 3)
  BNST(A4, 4) BNST(A5, 5) BNST(A6, 6) BNST(A7, 7)
  #undef BNST
  __syncthreads();

  if (t < 128) {
    int curv = -1; float curm = 0.f;
    for (int i = 0; i < STRETCH; ++i) {
      int v = svid[i];
      if (v != curv) {
        if (curv >= 0) {
          unsigned int vstart = voxloc[curv] + bexc[curv >> 8];
          unsigned int n = (unsigned int)vcnt[curv];
          if (vstart >= sbeg && vstart + n <= sbeg + STRETCH)
            outp[(size_t)curv * 128 + t] = curm;
          else
            atomicMax((unsigned int*)&outp[(size_t)curv * 128 + t],
                      __float_as_uint(curm));
        }
        curv = v;
        curm = sfeat[i][t];
      } else {
        curm = fmaxf(curm, sfeat[i][t]);
      }
    }
    if (curv >= 0) {
      unsigned int vstart = voxloc[curv] + bexc[curv >> 8];
      unsigned int n = (unsigned int)vcnt[curv];
      if (vstart >= sbeg && vstart + n <= sbeg + STRETCH)
        outp[(size_t)curv * 128 + t] = curm;
      else
        atomicMax((unsigned int*)&outp[(size_t)curv * 128 + t],
                  __float_as_uint(curm));
    }
  }
}

extern "C" void kernel_launch(void* const* d_in, const int* in_sizes, int n_in,
                              void* d_out, int out_size, void* d_ws, size_t ws_size,
                              hipStream_t stream) {
  const float* pts = (const float*)d_in[0];
  const float* W0  = (const float*)d_in[1];
  const float* g0  = (const float*)d_in[2];
  const float* b0  = (const float*)d_in[3];
  const float* W1  = (const float*)d_in[4];
  const float* g1  = (const float*)d_in[5];
  const float* b1  = (const float*)d_in[6];

  char* base = (char*)d_ws;
  double* stats = (double*)base;
  float*  fold  = (float*)(base + 3072);
  float*  vcnt  = (float*)(base + 4608);
  float*  vsx   = vcnt + NVOX;
  float*  vsy   = vsx + NVOX;
  float*  vsz   = vsy + NVOX;
  float*  vmax  = vsz + NVOX;                          // NVOX*64 f32 (72MB)
  unsigned int* voxloc = (unsigned int*)(vmax + (size_t)NVOX * 64);
  unsigned int* cursor = voxloc + NVOX;
  unsigned int* plist  = cursor + NVOX;
  unsigned int* vsort  = plist + NPTS;
  unsigned int* bsum   = vsort + NPTS;
  unsigned int* bexc   = bsum + SCANB;
  _Float16* Wf = (_Float16*)(bexc + SCANB);            // 32KB, 16B-aligned
  _Float16* h1 = Wf + 32 * 64 * 8;
  size_t need_fast = (size_t)((char*)h1 - base) + (size_t)NPTS * 128 * sizeof(_Float16);
  bool fast = ws_size >= need_fast;

  double* s0 = stats,       *q0 = stats + 64;
  double* s1 = stats + 128, *q1 = stats + 256;
  float* sc0 = fold,       *sh0 = fold + 64;
  float* sc1 = fold + 128, *sh1 = fold + 256;

  hipMemsetAsync(stats, 0, 3072, stream);
  hipMemsetAsync(vcnt, 0, (size_t)4 * NVOX * sizeof(float), stream);
  hipMemsetAsync(vmax, 0, (size_t)NVOX * 64 * sizeof(float), stream);
  hipMemsetAsync(cursor, 0, (size_t)NVOX * sizeof(unsigned int), stream);
  hipMemsetAsync(d_out, 0, (size_t)out_size * sizeof(float), stream);

  voxsum<<<NBLK, TPB, 0, stream>>>(pts, vcnt, vsx, vsy, vsz);
  scan1<<<SCANB, 256, 0, stream>>>(vcnt, voxloc, bsum);
  scan2<<<1, 64, 0, stream>>>(bsum, bexc);
  scatter<<<NBLK, TPB, 0, stream>>>(pts, voxloc, bexc, cursor, plist, vsort);
  bn0stats<<<NBLK, TPB, 0, stream>>>(pts, vcnt, vsx, vsy, vsz, W0, s0, q0);
  bnfold<<<1, 64, 0, stream>>>(s0, q0, g0, b0, sc0, sh0, 64);
  vmax0_stretch<<<FBLK, TPB, 0, stream>>>(pts, vcnt, vsx, vsy, vsz, voxloc, bexc,
                                          plist, W0, sc0, sh0, vmax);
  if (fast) {
    wconv<<<64, 256, 0, stream>>>(W1, Wf);
    gemm1m<<<SBLK2, TPB, 0, stream>>>(pts, vcnt, vsx, vsy, vsz, plist,
                                      W0, sc0, sh0, vmax, Wf, s1, q1, h1);
    bnfold<<<1, 128, 0, stream>>>(s1, q1, g1, b1, sc1, sh1, 128);
    final_cheap<<<FBLK, 128, 0, stream>>>(vsort, voxloc, bexc, vcnt,
                                          (const __half*)h1, sc1, sh1,
                                          (float*)d_out);
  } else {
    gemm1s_f32<<<SBLK2, TPB, 0, stream>>>(pts, vcnt, vsx, vsy, vsz, plist,
                                          W0, sc0, sh0, vmax, W1, s1, q1);
    bnfold<<<1, 128, 0, stream>>>(s1, q1, g1, b1, sc1, sh1, 128);
    final2<<<FBLK, TPB, 0, stream>>>(pts, vcnt, vsx, vsy, vsz, voxloc, bexc,
                                     plist, W0, sc0, sh0, vmax, W1, sc1, sh1,
                                     (float*)d_out);
  }
}

// Round 15
// 420.071 us; speedup vs baseline: 11.5759x; 1.0939x over previous
//
#include <hip/hip_runtime.h>
#include <hip/hip_fp16.h>
#include <stdint.h>

#define NPTS 400000
#define NVOX 281600
#define TPB  256
#define NBLK ((NPTS + TPB - 1) / TPB)
#define SCANB (NVOX / 256)       // 1100 exact
#define STRETCH 64
#define FBLK (NPTS / STRETCH)    // 6250 exact
#define SBLK2 1024

typedef _Float16 h8  __attribute__((ext_vector_type(8)));
typedef _Float16 h4v __attribute__((ext_vector_type(4)));
typedef float    f4  __attribute__((ext_vector_type(4)));

// XLA-style binning: division folded to multiply-by-reciprocal in f32.
// DO NOT CHANGE: exactly matches the golden (round 6->7 proof).
__device__ __forceinline__ int bin3(const float* __restrict__ pt,
                                    int& bx, int& by, int& bz) {
  float x = pt[1], y = pt[2], z = pt[3];
  bx = (int)fminf(fmaxf(floorf(x * 5.0f), 0.f), 351.f);
  by = (int)fminf(fmaxf(floorf((y + 40.f) * 5.0f), 0.f), 399.f);
  bz = (int)fminf(fmaxf(floorf((z + 3.f) * 0.25f), 0.f), 0.f);
  return (((int)pt[0] + bz) * 400 + by) * 352 + bx;
}

__device__ __forceinline__ int mkfeat(const float* __restrict__ pt,
    const float* __restrict__ vcnt, const float* __restrict__ vsx,
    const float* __restrict__ vsy, const float* __restrict__ vsz,
    float* f) {
  int bx, by, bz;
  int v = bin3(pt, bx, by, bz);
  float x = pt[1], y = pt[2], z = pt[3];
  float n = fmaxf(vcnt[v], 1.f);
  f[0] = x;  f[1] = y;  f[2] = z;  f[3] = pt[4];
  f[4] = x - vsx[v] / n;
  f[5] = y - vsy[v] / n;
  f[6] = z - vsz[v] / n;
  f[7] = x - (0.2f * (float)bx + 0.1f);
  f[8] = y - (0.2f * (float)by - 39.9f);
  f[9] = z - (4.0f * (float)bz - 1.0f);
  return v;
}

// ---------------- prologue ----------------
__global__ __launch_bounds__(256) void voxsum(const float* __restrict__ pts,
    float* __restrict__ vcnt, float* __restrict__ vsx,
    float* __restrict__ vsy, float* __restrict__ vsz) {
  int p = blockIdx.x * TPB + threadIdx.x;
  if (p >= NPTS) return;
  const float* pt = pts + (size_t)p * 5;
  int bx, by, bz;
  int v = bin3(pt, bx, by, bz);
  atomicAdd(&vcnt[v], 1.f);
  atomicAdd(&vsx[v], pt[1]);
  atomicAdd(&vsy[v], pt[2]);
  atomicAdd(&vsz[v], pt[3]);
}

__global__ __launch_bounds__(256) void bn0stats(const float* __restrict__ pts,
    const float* __restrict__ vcnt, const float* __restrict__ vsx,
    const float* __restrict__ vsy, const float* __restrict__ vsz,
    const float* __restrict__ W0,
    double* __restrict__ gs, double* __restrict__ gq) {
  __shared__ float bs[4][64], bq[4][64];
  int t = threadIdx.x, wv = t >> 6, ln = t & 63;
  int p = blockIdx.x * TPB + t;
  bool ok = p < NPTS;
  const float* pt = pts + (size_t)(ok ? p : 0) * 5;
  float f[10];
  mkfeat(pt, vcnt, vsx, vsy, vsz, f);
  for (int c = 0; c < 64; ++c) {
    float h = f[0] * W0[c];
    #pragma unroll
    for (int i = 1; i < 10; ++i) h = fmaf(f[i], W0[i * 64 + c], h);
    h = ok ? h : 0.f;
    float q = h * h;
    #pragma unroll
    for (int m = 1; m < 64; m <<= 1) {
      h += __shfl_xor(h, m, 64);
      q += __shfl_xor(q, m, 64);
    }
    if (ln == 0) { bs[wv][c] = h; bq[wv][c] = q; }
  }
  __syncthreads();
  if (t < 64) {
    atomicAdd(&gs[t], (double)bs[0][t] + bs[1][t] + bs[2][t] + bs[3][t]);
    atomicAdd(&gq[t], (double)bq[0][t] + bq[1][t] + bq[2][t] + bq[3][t]);
  }
}

__global__ void bnfold(const double* __restrict__ gs, const double* __restrict__ gq,
                       const float* __restrict__ gam, const float* __restrict__ bet,
                       float* __restrict__ sc, float* __restrict__ sh, int C) {
  int c = threadIdx.x;
  if (c >= C) return;
  double mu  = gs[c] / (double)NPTS;
  double var = gq[c] / (double)NPTS - mu * mu;
  double s = (double)gam[c] / sqrt(var + 1e-3);
  sc[c] = (float)s;
  sh[c] = (float)((double)bet[c] - mu * s);
}

// ---------------- counting sort ----------------
__global__ __launch_bounds__(256) void scan1(const float* __restrict__ vcnt,
    unsigned int* __restrict__ voxloc, unsigned int* __restrict__ bsum) {
  __shared__ unsigned int s[256];
  int t = threadIdx.x;
  int i = blockIdx.x * 256 + t;
  unsigned int val = (unsigned int)vcnt[i];
  s[t] = val;
  __syncthreads();
  for (int off = 1; off < 256; off <<= 1) {
    unsigned int add = (t >= off) ? s[t - off] : 0u;
    __syncthreads();
    s[t] += add;
    __syncthreads();
  }
  voxloc[i] = s[t] - val;
  if (t == 255) bsum[blockIdx.x] = s[t];
}

__global__ void scan2(const unsigned int* __restrict__ bsum,
                      unsigned int* __restrict__ bexc) {
  if (threadIdx.x != 0) return;
  unsigned int run = 0;
  for (int b = 0; b < SCANB; ++b) { bexc[b] = run; run += bsum[b]; }
}

// zero only the rows that need it: unoccupied out-rows; straddling voxels'
// out- and vmax-rows (the only atomicMax targets). Interior-occupied rows
// are fully overwritten by plain stores; unoccupied vmax rows never read.
__global__ __launch_bounds__(256) void prep(const float* __restrict__ vcnt,
    const unsigned int* __restrict__ voxloc, const unsigned int* __restrict__ bexc,
    float* __restrict__ vmax, float* __restrict__ outp) {
  int v = blockIdx.x * 256 + threadIdx.x;
  int n = (int)vcnt[v];
  f4 z = {0, 0, 0, 0};
  if (n == 0) {
    f4* o = (f4*)(outp + (size_t)v * 128);
    #pragma unroll
    for (int i = 0; i < 32; ++i) o[i] = z;
    return;
  }
  unsigned int vstart = voxloc[v] + bexc[v >> 8];
  bool interior = ((vstart & (STRETCH - 1)) + (unsigned)n) <= STRETCH;
  if (!interior) {
    f4* o = (f4*)(outp + (size_t)v * 128);
    #pragma unroll
    for (int i = 0; i < 32; ++i) o[i] = z;
    f4* m = (f4*)(vmax + (size_t)v * 64);
    #pragma unroll
    for (int i = 0; i < 16; ++i) m[i] = z;
  }
}

__global__ __launch_bounds__(256) void scatter(const float* __restrict__ pts,
    const unsigned int* __restrict__ voxloc, const unsigned int* __restrict__ bexc,
    unsigned int* __restrict__ cursor, unsigned int* __restrict__ plist,
    unsigned int* __restrict__ vsort) {
  int p = blockIdx.x * TPB + threadIdx.x;
  if (p >= NPTS) return;
  int bx, by, bz;
  int v = bin3(pts + (size_t)p * 5, bx, by, bz);
  unsigned int pos = voxloc[v] + bexc[v >> 8] + atomicAdd(&cursor[v], 1u);
  plist[pos] = (unsigned int)p;
  vsort[pos] = (unsigned int)v;
}

// ---------------- vmax0 over sorted stretches ----------------
__global__ __launch_bounds__(256) void vmax0_stretch(const float* __restrict__ pts,
    const float* __restrict__ vcnt, const float* __restrict__ vsx,
    const float* __restrict__ vsy, const float* __restrict__ vsz,
    const unsigned int* __restrict__ voxloc, const unsigned int* __restrict__ bexc,
    const unsigned int* __restrict__ plist,
    const float* __restrict__ W0, const float* __restrict__ sc0,
    const float* __restrict__ sh0, float* __restrict__ vmax) {
  __shared__ float sf[STRETCH][12];
  __shared__ int   svid[STRETCH];
  __shared__ float pf[STRETCH][64];
  int t = threadIdx.x;
  unsigned int sbeg = blockIdx.x * STRETCH;

  if (t < STRETCH) {
    unsigned int pidx = plist[sbeg + t];
    svid[t] = mkfeat(pts + (size_t)pidx * 5, vcnt, vsx, vsy, vsz, &sf[t][0]);
  }
  __syncthreads();
  for (int idx = t; idx < STRETCH * 64; idx += TPB) {
    int pt_ = idx >> 6, k = idx & 63;
    float h = sf[pt_][0] * W0[k];
    #pragma unroll
    for (int i = 1; i < 10; ++i) h = fmaf(sf[pt_][i], W0[i * 64 + k], h);
    pf[pt_][k] = fmaxf(fmaf(h, sc0[k], sh0[k]), 0.f);
  }
  __syncthreads();

  if (t < 64) {
    int curv = -1; float curm = 0.f;
    for (int i = 0; i < STRETCH; ++i) {
      int v = svid[i];
      if (v != curv) {
        if (curv >= 0) {
          unsigned int vstart = voxloc[curv] + bexc[curv >> 8];
          unsigned int n = (unsigned int)vcnt[curv];
          if (vstart >= sbeg && vstart + n <= sbeg + STRETCH)
            vmax[(size_t)curv * 64 + t] = curm;
          else
            atomicMax((unsigned int*)&vmax[(size_t)curv * 64 + t],
                      __float_as_uint(curm));
        }
        curv = v;
        curm = pf[i][t];
      } else {
        curm = fmaxf(curm, pf[i][t]);
      }
    }
    if (curv >= 0) {
      unsigned int vstart = voxloc[curv] + bexc[curv >> 8];
      unsigned int n = (unsigned int)vcnt[curv];
      if (vstart >= sbeg && vstart + n <= sbeg + STRETCH)
        vmax[(size_t)curv * 64 + t] = curm;
      else
        atomicMax((unsigned int*)&vmax[(size_t)curv * 64 + t],
                  __float_as_uint(curm));
    }
  }
}

// ---------------- W1 -> fragment-ordered fp16 ----------------
__global__ __launch_bounds__(256) void wconv(const float* __restrict__ W1,
                                             _Float16* __restrict__ Wf) {
  int idx = blockIdx.x * 256 + threadIdx.x;
  if (idx >= 32 * 64 * 8) return;
  int j = idx & 7, l = (idx >> 3) & 63, f = idx >> 9;
  int ks = f & 3, ntile = f >> 2;
  int k = ks * 32 + ((j >> 2) * 16) + 4 * (l >> 4) + (j & 3);
  int n = ntile * 16 + (l & 15);
  Wf[idx] = (_Float16)W1[k * 128 + n];
}

// ---------------- MFMA layer-1: stats + h1(fp16) in one pass ----------------
__device__ __forceinline__ h8 lda(const _Float16* __restrict__ r, int k0) {
  h4v lo = *(const h4v*)(r + k0);
  h4v hi = *(const h4v*)(r + k0 + 16);
  h8 a;
  a[0] = lo[0]; a[1] = lo[1]; a[2] = lo[2]; a[3] = lo[3];
  a[4] = hi[0]; a[5] = hi[1]; a[6] = hi[2]; a[7] = hi[3];
  return a;
}

__device__ __forceinline__ void emit_tile(f4 C, int ptb, int ch,
    _Float16* __restrict__ h1o, float& sf_, float& qf_) {
  float v0 = C[0], v1 = C[1], v2 = C[2], v3 = C[3];
  h1o[(size_t)(ptb + 0) * 128 + ch] = (_Float16)v0;
  h1o[(size_t)(ptb + 1) * 128 + ch] = (_Float16)v1;
  h1o[(size_t)(ptb + 2) * 128 + ch] = (_Float16)v2;
  h1o[(size_t)(ptb + 3) * 128 + ch] = (_Float16)v3;
  sf_ += (v0 + v1) + (v2 + v3);
  qf_ = fmaf(v0, v0, fmaf(v1, v1, fmaf(v2, v2, fmaf(v3, v3, qf_))));
}

__global__ __launch_bounds__(256) void gemm1m(const float* __restrict__ pts,
    const float* __restrict__ vcnt, const float* __restrict__ vsx,
    const float* __restrict__ vsy, const float* __restrict__ vsz,
    const unsigned int* __restrict__ plist,
    const float* __restrict__ W0, const float* __restrict__ sc0,
    const float* __restrict__ sh0, const float* __restrict__ vmax,
    const _Float16* __restrict__ Wf,
    double* __restrict__ gs, double* __restrict__ gq,
    _Float16* __restrict__ h1out) {
  __shared__ float sf[STRETCH][12];
  __shared__ int   svid[STRETCH];
  __shared__ __align__(16) _Float16 fh[64][140];   // 280B rows: <=2-way banks

  int t = threadIdx.x;
  int w = t >> 6, l = t & 63;
  int lm = l & 15, lg = l >> 4;

  const h8* wfv = (const h8*)Wf;
  h8 B00 = wfv[((w * 2 + 0) * 4 + 0) * 64 + l];
  h8 B01 = wfv[((w * 2 + 0) * 4 + 1) * 64 + l];
  h8 B02 = wfv[((w * 2 + 0) * 4 + 2) * 64 + l];
  h8 B03 = wfv[((w * 2 + 0) * 4 + 3) * 64 + l];
  h8 B10 = wfv[((w * 2 + 1) * 4 + 0) * 64 + l];
  h8 B11 = wfv[((w * 2 + 1) * 4 + 1) * 64 + l];
  h8 B12 = wfv[((w * 2 + 1) * 4 + 2) * 64 + l];
  h8 B13 = wfv[((w * 2 + 1) * 4 + 3) * 64 + l];

  double sd0 = 0, sd1 = 0, qd0 = 0, qd1 = 0;

  for (int tile = blockIdx.x; tile < FBLK; tile += gridDim.x) {
    unsigned int sbeg = tile * STRETCH;
    if (t < STRETCH) {
      unsigned int pidx = plist[sbeg + t];
      svid[t] = mkfeat(pts + (size_t)pidx * 5, vcnt, vsx, vsy, vsz, &sf[t][0]);
    }
    __syncthreads();
    for (int idx = t; idx < STRETCH * 64; idx += TPB) {
      int p_ = idx >> 6, k = idx & 63;
      float h = sf[p_][0] * W0[k];
      #pragma unroll
      for (int i = 1; i < 10; ++i) h = fmaf(sf[p_][i], W0[i * 64 + k], h);
      fh[p_][k] = (_Float16)fmaxf(fmaf(h, sc0[k], sh0[k]), 0.f);
    }
    for (int idx = t; idx < STRETCH * 64; idx += TPB) {
      int p_ = idx >> 6, k = idx & 63;
      fh[p_][64 + k] = (_Float16)vmax[(size_t)svid[p_] * 64 + k];
    }
    __syncthreads();

    f4 C00 = {0,0,0,0}, C01 = {0,0,0,0}, C10 = {0,0,0,0}, C11 = {0,0,0,0};
    f4 C20 = {0,0,0,0}, C21 = {0,0,0,0}, C30 = {0,0,0,0}, C31 = {0,0,0,0};

    #define DO_MT(mt, CA, CB) {                                              \
      const _Float16* r = &fh[(mt) * 16 + lm][0];                            \
      h8 A0 = lda(r, 0 * 32 + 4 * lg);                                       \
      h8 A1 = lda(r, 1 * 32 + 4 * lg);                                       \
      h8 A2 = lda(r, 2 * 32 + 4 * lg);                                       \
      h8 A3 = lda(r, 3 * 32 + 4 * lg);                                       \
      CA = __builtin_amdgcn_mfma_f32_16x16x32_f16(A0, B00, CA, 0, 0, 0);     \
      CA = __builtin_amdgcn_mfma_f32_16x16x32_f16(A1, B01, CA, 0, 0, 0);     \
      CA = __builtin_amdgcn_mfma_f32_16x16x32_f16(A2, B02, CA, 0, 0, 0);     \
      CA = __builtin_amdgcn_mfma_f32_16x16x32_f16(A3, B03, CA, 0, 0, 0);     \
      CB = __builtin_amdgcn_mfma_f32_16x16x32_f16(A0, B10, CB, 0, 0, 0);     \
      CB = __builtin_amdgcn_mfma_f32_16x16x32_f16(A1, B11, CB, 0, 0, 0);     \
      CB = __builtin_amdgcn_mfma_f32_16x16x32_f16(A2, B12, CB, 0, 0, 0);     \
      CB = __builtin_amdgcn_mfma_f32_16x16x32_f16(A3, B13, CB, 0, 0, 0); }
    DO_MT(0, C00, C01)
    DO_MT(1, C10, C11)
    DO_MT(2, C20, C21)
    DO_MT(3, C30, C31)
    #undef DO_MT

    float s0f = 0, q0f = 0, s1f = 0, q1f = 0;
    int ch0 = w * 32 + lm, ch1 = w * 32 + 16 + lm;
    emit_tile(C00, sbeg + 0 * 16 + lg * 4, ch0, h1out, s0f, q0f);
    emit_tile(C01, sbeg + 0 * 16 + lg * 4, ch1, h1out, s1f, q1f);
    emit_tile(C10, sbeg + 1 * 16 + lg * 4, ch0, h1out, s0f, q0f);
    emit_tile(C11, sbeg + 1 * 16 + lg * 4, ch1, h1out, s1f, q1f);
    emit_tile(C20, sbeg + 2 * 16 + lg * 4, ch0, h1out, s0f, q0f);
    emit_tile(C21, sbeg + 2 * 16 + lg * 4, ch1, h1out, s1f, q1f);
    emit_tile(C30, sbeg + 3 * 16 + lg * 4, ch0, h1out, s0f, q0f);
    emit_tile(C31, sbeg + 3 * 16 + lg * 4, ch1, h1out, s1f, q1f);
    sd0 += (double)s0f; qd0 += (double)q0f;
    sd1 += (double)s1f; qd1 += (double)q1f;
    __syncthreads();
  }

  sd0 += __shfl_xor(sd0, 16, 64); sd0 += __shfl_xor(sd0, 32, 64);
  qd0 += __shfl_xor(qd0, 16, 64); qd0 += __shfl_xor(qd0, 32, 64);
  sd1 += __shfl_xor(sd1, 16, 64); sd1 += __shfl_xor(sd1, 32, 64);
  qd1 += __shfl_xor(qd1, 16, 64); qd1 += __shfl_xor(qd1, 32, 64);
  if (lg == 0) {
    atomicAdd(&gs[w * 32 + lm], sd0);
    atomicAdd(&gq[w * 32 + lm], qd0);
    atomicAdd(&gs[w * 32 + 16 + lm], sd1);
    atomicAdd(&gq[w * 32 + 16 + lm], qd1);
  }
}

// ---- fast final: wave-per-stretch, half2 channels, BN+ReLU, seg-max ----
__global__ __launch_bounds__(256) void final_cheap(
    const unsigned int* __restrict__ vsort,
    const unsigned int* __restrict__ voxloc, const unsigned int* __restrict__ bexc,
    const float* __restrict__ vcnt, const _Float16* __restrict__ h1,
    const float* __restrict__ sc1, const float* __restrict__ sh1,
    float* __restrict__ outp) {
  int t = threadIdx.x, w = t >> 6, l = t & 63;
  int s = blockIdx.x * 4 + w;
  if (s >= FBLK) return;
  unsigned int sbeg = (unsigned int)s * STRETCH;
  float2 sv = *(const float2*)(sc1 + 2 * l);
  float2 bv = *(const float2*)(sh1 + 2 * l);

  int curv = -1; float m0 = 0.f, m1 = 0.f;
  #define FLUSH()                                                            \
    { unsigned int vstart = voxloc[curv] + bexc[curv >> 8];                  \
      unsigned int n = (unsigned int)vcnt[curv];                             \
      if (vstart >= sbeg && vstart + n <= sbeg + STRETCH) {                  \
        *(float2*)(outp + (size_t)curv * 128 + 2 * l) = make_float2(m0, m1); \
      } else {                                                               \
        atomicMax((unsigned int*)&outp[(size_t)curv * 128 + 2 * l],          \
                  __float_as_uint(m0));                                      \
        atomicMax((unsigned int*)&outp[(size_t)curv * 128 + 2 * l + 1],      \
                  __float_as_uint(m1));                                      \
      } }
  for (int i = 0; i < STRETCH; ++i) {
    int v = (int)vsort[sbeg + i];
    __half2 hv = *(const __half2*)(h1 + (size_t)(sbeg + i) * 128 + 2 * l);
    float2 hf = __half22float2(hv);
    float v0 = fmaxf(fmaf(hf.x, sv.x, bv.x), 0.f);
    float v1 = fmaxf(fmaf(hf.y, sv.y, bv.y), 0.f);
    if (v != curv) {
      if (curv >= 0) FLUSH()
      curv = v; m0 = v0; m1 = v1;
    } else {
      m0 = fmaxf(m0, v0);
      m1 = fmaxf(m1, v1);
    }
  }
  if (curv >= 0) FLUSH()
  #undef FLUSH
}

// ---------------- fp32 fallback path (proven) ----------------
#define TILE_STAGE(sbeg_)                                                    \
  if (t < STRETCH) {                                                         \
    unsigned int pidx = plist[(sbeg_) + t];                                  \
    svid[t] = mkfeat(pts + (size_t)pidx * 5, vcnt, vsx, vsy, vsz, &sf[t][0]);\
  }                                                                          \
  __syncthreads();                                                           \
  for (int idx = t; idx < STRETCH * 64; idx += TPB) {                        \
    int pt_ = idx >> 6, k = idx & 63;                                        \
    float h = sf[pt_][0] * W0[k];                                            \
    _Pragma("unroll")                                                        \
    for (int i = 1; i < 10; ++i) h = fmaf(sf[pt_][i], W0[i * 64 + k], h);    \
    sfeat[pt_][k] = fmaxf(fmaf(h, sc0[k], sh0[k]), 0.f);                     \
  }                                                                          \
  for (int idx = t; idx < STRETCH * 64; idx += TPB) {                        \
    int pt_ = idx >> 6, k = idx & 63;                                        \
    sfeat[pt_][64 + k] = vmax[(size_t)svid[pt_] * 64 + k];                   \
  }                                                                          \
  __syncthreads();

#define TILE_GEMM()                                                          \
  const float* r0 = sfeat[pg * 8 + 0];                                       \
  const float* r1 = sfeat[pg * 8 + 1];                                       \
  const float* r2 = sfeat[pg * 8 + 2];                                       \
  const float* r3 = sfeat[pg * 8 + 3];                                       \
  const float* r4 = sfeat[pg * 8 + 4];                                       \
  const float* r5 = sfeat[pg * 8 + 5];                                       \
  const float* r6 = sfeat[pg * 8 + 6];                                       \
  const float* r7 = sfeat[pg * 8 + 7];                                       \
  float4 A0 = {0,0,0,0}, A1 = {0,0,0,0}, A2 = {0,0,0,0}, A3 = {0,0,0,0};     \
  float4 A4 = {0,0,0,0}, A5 = {0,0,0,0}, A6 = {0,0,0,0}, A7 = {0,0,0,0};     \
  _Pragma("unroll 8")                                                        \
  for (int k = 0; k < 128; ++k) {                                            \
    float4 w = *reinterpret_cast<const float4*>(W1 + (size_t)k * 128 + cb*4);\
    float p0 = r0[k], p1_ = r1[k], p2 = r2[k], p3 = r3[k];                   \
    float p4 = r4[k], p5 = r5[k], p6 = r6[k], p7 = r7[k];                    \
    A0.x = fmaf(p0, w.x, A0.x); A0.y = fmaf(p0, w.y, A0.y);                  \
    A0.z = fmaf(p0, w.z, A0.z); A0.w = fmaf(p0, w.w, A0.w);                  \
    A1.x = fmaf(p1_, w.x, A1.x); A1.y = fmaf(p1_, w.y, A1.y);                \
    A1.z = fmaf(p1_, w.z, A1.z); A1.w = fmaf(p1_, w.w, A1.w);                \
    A2.x = fmaf(p2, w.x, A2.x); A2.y = fmaf(p2, w.y, A2.y);                  \
    A2.z = fmaf(p2, w.z, A2.z); A2.w = fmaf(p2, w.w, A2.w);                  \
    A3.x = fmaf(p3, w.x, A3.x); A3.y = fmaf(p3, w.y, A3.y);                  \
    A3.z = fmaf(p3, w.z, A3.z); A3.w = fmaf(p3, w.w, A3.w);                  \
    A4.x = fmaf(p4, w.x, A4.x); A4.y = fmaf(p4, w.y, A4.y);                  \
    A4.z = fmaf(p4, w.z, A4.z); A4.w = fmaf(p4, w.w, A4.w);                  \
    A5.x = fmaf(p5, w.x, A5.x); A5.y = fmaf(p5, w.y, A5.y);                  \
    A5.z = fmaf(p5, w.z, A5.z); A5.w = fmaf(p5, w.w, A5.w);                  \
    A6.x = fmaf(p6, w.x, A6.x); A6.y = fmaf(p6, w.y, A6.y);                  \
    A6.z = fmaf(p6, w.z, A6.z); A6.w = fmaf(p6, w.w, A6.w);                  \
    A7.x = fmaf(p7, w.x, A7.x); A7.y = fmaf(p7, w.y, A7.y);                  \
    A7.z = fmaf(p7, w.z, A7.z); A7.w = fmaf(p7, w.w, A7.w);                  \
  }

__global__ __launch_bounds__(256) void gemm1s_f32(const float* __restrict__ pts,
    const float* __restrict__ vcnt, const float* __restrict__ vsx,
    const float* __restrict__ vsy, const float* __restrict__ vsz,
    const unsigned int* __restrict__ plist,
    const float* __restrict__ W0, const float* __restrict__ sc0,
    const float* __restrict__ sh0, const float* __restrict__ vmax,
    const float* __restrict__ W1,
    double* __restrict__ gs, double* __restrict__ gq) {
  union SM {
    struct { float sf[STRETCH][12]; int svid[STRETCH]; float sfeat[STRETCH][128]; } a;
    struct { double lsum[8 * 128]; double lsq[8 * 128]; } b;
  };
  __shared__ SM sm;
  auto& sf = sm.a.sf;
  auto& svid = sm.a.svid;
  auto& sfeat = sm.a.sfeat;

  int t = threadIdx.x;
  int pg = t >> 5, cb = t & 31;
  double sd0 = 0, sd1 = 0, sd2 = 0, sd3 = 0;
  double qd0 = 0, qd1 = 0, qd2 = 0, qd3 = 0;

  for (int tile = blockIdx.x; tile < FBLK; tile += gridDim.x) {
    unsigned int sbeg = tile * STRETCH;
    TILE_STAGE(sbeg)
    TILE_GEMM()
    sd0 += (double)A0.x + (double)A1.x + (double)A2.x + (double)A3.x
         + (double)A4.x + (double)A5.x + (double)A6.x + (double)A7.x;
    sd1 += (double)A0.y + (double)A1.y + (double)A2.y + (double)A3.y
         + (double)A4.y + (double)A5.y + (double)A6.y + (double)A7.y;
    sd2 += (double)A0.z + (double)A1.z + (double)A2.z + (double)A3.z
         + (double)A4.z + (double)A5.z + (double)A6.z + (double)A7.z;
    sd3 += (double)A0.w + (double)A1.w + (double)A2.w + (double)A3.w
         + (double)A4.w + (double)A5.w + (double)A6.w + (double)A7.w;
    qd0 += (double)A0.x*A0.x + (double)A1.x*A1.x + (double)A2.x*A2.x + (double)A3.x*A3.x
         + (double)A4.x*A4.x + (double)A5.x*A5.x + (double)A6.x*A6.x + (double)A7.x*A7.x;
    qd1 += (double)A0.y*A0.y + (double)A1.y*A1.y + (double)A2.y*A2.y + (double)A3.y*A3.y
         + (double)A4.y*A4.y + (double)A5.y*A5.y + (double)A6.y*A6.y + (double)A7.y*A7.y;
    qd2 += (double)A0.z*A0.z + (double)A1.z*A1.z + (double)A2.z*A2.z + (double)A3.z*A3.z
         + (double)A4.z*A4.z + (double)A5.z*A5.z + (double)A6.z*A6.z + (double)A7.z*A7.z;
    qd3 += (double)A0.w*A0.w + (double)A1.w*A1.w + (double)A2.w*A2.w + (double)A3.w*A3.w
         + (double)A4.w*A4.w + (double)A5.w*A5.w + (double)A6.w*A6.w + (double)A7.w*A7.w;
    __syncthreads();
  }

  int c = cb * 4;
  sm.b.lsum[pg * 128 + c + 0] = sd0;  sm.b.lsq[pg * 128 + c + 0] = qd0;
  sm.b.lsum[pg * 128 + c + 1] = sd1;  sm.b.lsq[pg * 128 + c + 1] = qd1;
  sm.b.lsum[pg * 128 + c + 2] = sd2;  sm.b.lsq[pg * 128 + c + 2] = qd2;
  sm.b.lsum[pg * 128 + c + 3] = sd3;  sm.b.lsq[pg * 128 + c + 3] = qd3;
  __syncthreads();
  if (t < 128) {
    double S = 0, Q = 0;
    #pragma unroll
    for (int j = 0; j < 8; ++j) { S += sm.b.lsum[j * 128 + t]; Q += sm.b.lsq[j * 128 + t]; }
    atomicAdd(&gs[t], S);
    atomicAdd(&gq[t], Q);
  }
}

__global__ __launch_bounds__(256) void final2(const float* __restrict__ pts,
    const float* __restrict__ vcnt, const float* __restrict__ vsx,
    const float* __restrict__ vsy, const float* __restrict__ vsz,
    const unsigned int* __restrict__ voxloc, const unsigned int* __restrict__ bexc,
    const unsigned int* __restrict__ plist,
    const float* __restrict__ W0, const float* __restrict__ sc0,
    const float* __restrict__ sh0, const float* __restrict__ vmax,
    const float* __restrict__ W1, const float* __restrict__ sc1,
    const float* __restrict__ sh1, float* __restrict__ outp) {
  __shared__ float sf[STRETCH][12];
  __shared__ int   svid[STRETCH];
  __shared__ float sfeat[STRETCH][128];

  int t = threadIdx.x;
  int pg = t >> 5, cb = t & 31;
  unsigned int sbeg = blockIdx.x * STRETCH;

  TILE_STAGE(sbeg)
  TILE_GEMM()
  __syncthreads();

  int c = cb * 4;
  float4 s1v = *reinterpret_cast<const float4*>(sc1 + c);
  float4 h1v = *reinterpret_cast<const float4*>(sh1 + c);
  #define BNST(Aj, j)                                                        \
    { float4 P;                                                              \
      P.x = fmaxf(fmaf(Aj.x, s1v.x, h1v.x), 0.f);                            \
      P.y = fmaxf(fmaf(Aj.y, s1v.y, h1v.y), 0.f);                            \
      P.z = fmaxf(fmaf(Aj.z, s1v.z, h1v.z), 0.f);                            \
      P.w = fmaxf(fmaf(Aj.w, s1v.w, h1v.w), 0.f);                            \
      *reinterpret_cast<float4*>(&sfeat[pg * 8 + j][c]) = P; }
  BNST(A0, 0) BNST(A1, 1) BNST(A2, 2) BNST(A3, 3)
  BNST(A4, 4) BNST(A5, 5) BNST(A6, 6) BNST(A7, 7)
  #undef BNST
  __syncthreads();

  if (t < 128) {
    int curv = -1; float curm = 0.f;
    for (int i = 0; i < STRETCH; ++i) {
      int v = svid[i];
      if (v != curv) {
        if (curv >= 0) {
          unsigned int vstart = voxloc[curv] + bexc[curv >> 8];
          unsigned int n = (unsigned int)vcnt[curv];
          if (vstart >= sbeg && vstart + n <= sbeg + STRETCH)
            outp[(size_t)curv * 128 + t] = curm;
          else
            atomicMax((unsigned int*)&outp[(size_t)curv * 128 + t],
                      __float_as_uint(curm));
        }
        curv = v;
        curm = sfeat[i][t];
      } else {
        curm = fmaxf(curm, sfeat[i][t]);
      }
    }
    if (curv >= 0) {
      unsigned int vstart = voxloc[curv] + bexc[curv >> 8];
      unsigned int n = (unsigned int)vcnt[curv];
      if (vstart >= sbeg && vstart + n <= sbeg + STRETCH)
        outp[(size_t)curv * 128 + t] = curm;
      else
        atomicMax((unsigned int*)&outp[(size_t)curv * 128 + t],
                  __float_as_uint(curm));
    }
  }
}

extern "C" void kernel_launch(void* const* d_in, const int* in_sizes, int n_in,
                              void* d_out, int out_size, void* d_ws, size_t ws_size,
                              hipStream_t stream) {
  const float* pts = (const float*)d_in[0];
  const float* W0  = (const float*)d_in[1];
  const float* g0  = (const float*)d_in[2];
  const float* b0  = (const float*)d_in[3];
  const float* W1  = (const float*)d_in[4];
  const float* g1  = (const float*)d_in[5];
  const float* b1  = (const float*)d_in[6];

  char* base = (char*)d_ws;
  double* stats = (double*)base;
  float*  fold  = (float*)(base + 3072);
  float*  vcnt  = (float*)(base + 4608);
  float*  vsx   = vcnt + NVOX;
  float*  vsy   = vsx + NVOX;
  float*  vsz   = vsy + NVOX;
  float*  vmax  = vsz + NVOX;                          // NVOX*64 f32 (72MB)
  unsigned int* voxloc = (unsigned int*)(vmax + (size_t)NVOX * 64);
  unsigned int* cursor = voxloc + NVOX;
  unsigned int* plist  = cursor + NVOX;
  unsigned int* vsort  = plist + NPTS;
  unsigned int* bsum   = vsort + NPTS;
  unsigned int* bexc   = bsum + SCANB;
  _Float16* Wf = (_Float16*)(bexc + SCANB);            // 32KB, 16B-aligned
  _Float16* h1 = Wf + 32 * 64 * 8;
  size_t need_fast = (size_t)((char*)h1 - base) + (size_t)NPTS * 128 * sizeof(_Float16);
  bool fast = ws_size >= need_fast;

  double* s0 = stats,       *q0 = stats + 64;
  double* s1 = stats + 128, *q1 = stats + 256;
  float* sc0 = fold,       *sh0 = fold + 64;
  float* sc1 = fold + 128, *sh1 = fold + 256;

  hipMemsetAsync(stats, 0, 3072, stream);
  hipMemsetAsync(vcnt, 0, (size_t)4 * NVOX * sizeof(float), stream);
  hipMemsetAsync(cursor, 0, (size_t)NVOX * sizeof(unsigned int), stream);

  voxsum<<<NBLK, TPB, 0, stream>>>(pts, vcnt, vsx, vsy, vsz);
  scan1<<<SCANB, 256, 0, stream>>>(vcnt, voxloc, bsum);
  scan2<<<1, 64, 0, stream>>>(bsum, bexc);
  prep<<<SCANB, 256, 0, stream>>>(vcnt, voxloc, bexc, vmax, (float*)d_out);
  scatter<<<NBLK, TPB, 0, stream>>>(pts, voxloc, bexc, cursor, plist, vsort);
  bn0stats<<<NBLK, TPB, 0, stream>>>(pts, vcnt, vsx, vsy, vsz, W0, s0, q0);
  bnfold<<<1, 64, 0, stream>>>(s0, q0, g0, b0, sc0, sh0, 64);
  vmax0_stretch<<<FBLK, TPB, 0, stream>>>(pts, vcnt, vsx, vsy, vsz, voxloc, bexc,
                                          plist, W0, sc0, sh0, vmax);
  if (fast) {
    wconv<<<64, 256, 0, stream>>>(W1, Wf);
    gemm1m<<<SBLK2, TPB, 0, stream>>>(pts, vcnt, vsx, vsy, vsz, plist,
                                      W0, sc0, sh0, vmax, Wf, s1, q1, h1);
    bnfold<<<1, 128, 0, stream>>>(s1, q1, g1, b1, sc1, sh1, 128);
    final_cheap<<<(FBLK + 3) / 4, 256, 0, stream>>>(vsort, voxloc, bexc, vcnt,
                                                    h1, sc1, sh1, (float*)d_out);
  } else {
    gemm1s_f32<<<SBLK2, TPB, 0, stream>>>(pts, vcnt, vsx, vsy, vsz, plist,
                                          W0, sc0, sh0, vmax, W1, s1, q1);
    bnfold<<<1, 128, 0, stream>>>(s1, q1, g1, b1, sc1, sh1, 128);
    final2<<<FBLK, TPB, 0, stream>>>(pts, vcnt, vsx, vsy, vsz, voxloc, bexc,
                                     plist, W0, sc0, sh0, vmax, W1, sc1, sh1,
                                     (float*)d_out);
  }
}